// Round 2
// baseline (6390.085 us; speedup 1.0000x reference)
//
#include <hip/hip_runtime.h>
#include <cstdint>
#include <cstddef>

#define B_ROWS 1024
#define N_CAND 50000
#define CTX    96
#define D_IN   128
#define D_MAIN 256
#define D_BLOCK 512
#define N_OUT  10
#define LN_EPS 1e-5f

// chunking (memory safety: keep total workspace ~84 MB)
#define RC_ENC 6250     // candidate-encoder row chunk (8 chunks)
#define MB_CH  128      // distance/top-k query-row chunk (8 chunks)
#define BB_CH  64       // T-MLP batch-row chunk (16 chunks)

// ---------------------------------------------------------------------------
// Generic fp32 GEMM (NN): C = act(A[MxK] @ B[KxN] + bias[N]) (+ R[MxN])
// 64x64 block tile, BK=16, 256 threads, 4x4 micro-tile per thread.
// ---------------------------------------------------------------------------
template<bool RELU, bool HAS_BIAS, bool HAS_RES>
__global__ __launch_bounds__(256)
void gemm_nn(const float* __restrict__ A, const float* __restrict__ Bm,
             const float* __restrict__ bias, const float* __restrict__ Rm,
             float* __restrict__ C, int M, int N, int K)
{
    __shared__ float As[16][64];   // transposed: As[k][m]
    __shared__ float Bs[16][64];   // Bs[k][n]
    const int tid = threadIdx.x;
    const int bm = blockIdx.y * 64;
    const int bn = blockIdx.x * 64;

    const int a_m = tid >> 2;          // 0..63
    const int a_k = (tid & 3) << 2;    // 0,4,8,12
    const int b_k = tid >> 4;          // 0..15
    const int b_n = (tid & 15) << 2;   // 0..60

    const int my = (tid >> 4) << 2;    // row group 0..60
    const int nx = (tid & 15) << 2;    // col group 0..60

    float acc[4][4] = {};

    for (int k0 = 0; k0 < K; k0 += 16) {
        // load A tile (K is always a multiple of 16, rows guarded)
        float4 av = make_float4(0.f, 0.f, 0.f, 0.f);
        const int gm = bm + a_m;
        if (gm < M) av = *(const float4*)(A + (size_t)gm * K + k0 + a_k);
        As[a_k + 0][a_m] = av.x;
        As[a_k + 1][a_m] = av.y;
        As[a_k + 2][a_m] = av.z;
        As[a_k + 3][a_m] = av.w;

        // load B tile
        float4 bv = make_float4(0.f, 0.f, 0.f, 0.f);
        const int gn = bn + b_n;
        const float* bp = Bm + (size_t)(k0 + b_k) * N + gn;
        if (gn + 3 < N && (N & 3) == 0) {
            bv = *(const float4*)bp;
        } else {
            if (gn + 0 < N) bv.x = bp[0];
            if (gn + 1 < N) bv.y = bp[1];
            if (gn + 2 < N) bv.z = bp[2];
            if (gn + 3 < N) bv.w = bp[3];
        }
        *(float4*)&Bs[b_k][b_n] = bv;

        __syncthreads();
        #pragma unroll
        for (int k = 0; k < 16; ++k) {
            const float4 a4 = *(const float4*)&As[k][my];
            const float4 b4 = *(const float4*)&Bs[k][nx];
            const float a[4] = {a4.x, a4.y, a4.z, a4.w};
            const float b[4] = {b4.x, b4.y, b4.z, b4.w};
            #pragma unroll
            for (int i = 0; i < 4; ++i)
                #pragma unroll
                for (int j = 0; j < 4; ++j)
                    acc[i][j] = fmaf(a[i], b[j], acc[i][j]);
        }
        __syncthreads();
    }

    #pragma unroll
    for (int i = 0; i < 4; ++i) {
        const int m = bm + my + i;
        if (m >= M) continue;
        #pragma unroll
        for (int j = 0; j < 4; ++j) {
            const int n = bn + nx + j;
            if (n >= N) continue;
            float v = acc[i][j];
            if (HAS_BIAS) v += bias[n];
            if (RELU)     v = fmaxf(v, 0.f);
            if (HAS_RES)  v += Rm[(size_t)m * N + n];
            C[(size_t)m * N + n] = v;
        }
    }
}

// ---------------------------------------------------------------------------
// GEMM (NT) for the kNN distance: C[m,n] = -2 * sum_k A[m,k]*B[n,k] + nb[n]
// ---------------------------------------------------------------------------
__global__ __launch_bounds__(256)
void gemm_nt_dist(const float* __restrict__ A, const float* __restrict__ Bm,
                  const float* __restrict__ nb, float* __restrict__ C,
                  int M, int N, int K)
{
    __shared__ float As[16][64];
    __shared__ float Bs[16][64];
    const int tid = threadIdx.x;
    const int bm = blockIdx.y * 64;
    const int bn = blockIdx.x * 64;

    const int a_m = tid >> 2;
    const int a_k = (tid & 3) << 2;
    const int my = (tid >> 4) << 2;
    const int nx = (tid & 15) << 2;

    float acc[4][4] = {};

    for (int k0 = 0; k0 < K; k0 += 16) {
        float4 av = make_float4(0.f, 0.f, 0.f, 0.f);
        const int gm = bm + a_m;
        if (gm < M) av = *(const float4*)(A + (size_t)gm * K + k0 + a_k);
        As[a_k + 0][a_m] = av.x;
        As[a_k + 1][a_m] = av.y;
        As[a_k + 2][a_m] = av.z;
        As[a_k + 3][a_m] = av.w;

        float4 bv = make_float4(0.f, 0.f, 0.f, 0.f);
        const int gn = bn + a_m;
        if (gn < N) bv = *(const float4*)(Bm + (size_t)gn * K + k0 + a_k);
        Bs[a_k + 0][a_m] = bv.x;
        Bs[a_k + 1][a_m] = bv.y;
        Bs[a_k + 2][a_m] = bv.z;
        Bs[a_k + 3][a_m] = bv.w;

        __syncthreads();
        #pragma unroll
        for (int k = 0; k < 16; ++k) {
            const float4 a4 = *(const float4*)&As[k][my];
            const float4 b4 = *(const float4*)&Bs[k][nx];
            const float a[4] = {a4.x, a4.y, a4.z, a4.w};
            const float b[4] = {b4.x, b4.y, b4.z, b4.w};
            #pragma unroll
            for (int i = 0; i < 4; ++i)
                #pragma unroll
                for (int j = 0; j < 4; ++j)
                    acc[i][j] = fmaf(a[i], b[j], acc[i][j]);
        }
        __syncthreads();
    }

    #pragma unroll
    for (int i = 0; i < 4; ++i) {
        const int m = bm + my + i;
        if (m >= M) continue;
        #pragma unroll
        for (int j = 0; j < 4; ++j) {
            const int n = bn + nx + j;
            if (n >= N) continue;
            C[(size_t)m * N + n] = -2.f * acc[i][j] + nb[n];
        }
    }
}

// ---------------------------------------------------------------------------
// LayerNorm over D_MAIN=256 columns, one block per row.
// ---------------------------------------------------------------------------
template<bool RELU>
__global__ __launch_bounds__(256)
void ln_kernel(const float* __restrict__ X, const float* __restrict__ g,
               const float* __restrict__ b, float* __restrict__ Y)
{
    const int row = blockIdx.x, tid = threadIdx.x;
    const float x = X[(size_t)row * D_MAIN + tid];
    __shared__ float red[4];
    const int lane = tid & 63, wid = tid >> 6;

    float s = x;
    #pragma unroll
    for (int off = 32; off; off >>= 1) s += __shfl_down(s, off, 64);
    if (lane == 0) red[wid] = s;
    __syncthreads();
    const float mean = (red[0] + red[1] + red[2] + red[3]) * (1.f / D_MAIN);
    __syncthreads();

    const float xm = x - mean;
    s = xm * xm;
    #pragma unroll
    for (int off = 32; off; off >>= 1) s += __shfl_down(s, off, 64);
    if (lane == 0) red[wid] = s;
    __syncthreads();
    const float var = (red[0] + red[1] + red[2] + red[3]) * (1.f / D_MAIN);

    float y = xm / sqrtf(var + LN_EPS) * g[tid] + b[tid];
    if (RELU) y = fmaxf(y, 0.f);
    Y[(size_t)row * D_MAIN + tid] = y;
}

// ---------------------------------------------------------------------------
// ||cand_k[n]||^2 — one wave per row.
// ---------------------------------------------------------------------------
__global__ __launch_bounds__(64)
void cn2_kernel(const float* __restrict__ ck, float* __restrict__ out)
{
    const int row = blockIdx.x, lane = threadIdx.x;
    const float4 v = *(const float4*)(ck + (size_t)row * D_MAIN + lane * 4);
    float s = v.x * v.x + v.y * v.y + v.z * v.z + v.w * v.w;
    #pragma unroll
    for (int off = 32; off; off >>= 1) s += __shfl_down(s, off, 64);
    if (lane == 0) out[row] = s;
}

// ---------------------------------------------------------------------------
// Exact top-96 smallest per row via 4-pass radix select on monotonic u32 key.
// One block (256 threads) per row. Order within the 96 is arbitrary (the
// consumer — softmax + weighted sum — is permutation-invariant).
// ---------------------------------------------------------------------------
__device__ __forceinline__ unsigned f2u_mono(float f) {
    unsigned u = __float_as_uint(f);
    return u ^ ((u & 0x80000000u) ? 0xFFFFFFFFu : 0x80000000u);
}

__global__ __launch_bounds__(256)
void topk96_kernel(const float* __restrict__ S, int* __restrict__ idx_out,
                   float* __restrict__ sval_out)
{
    const int row = blockIdx.x;
    const float* srow = S + (size_t)row * N_CAND;
    const int tid = threadIdx.x;

    __shared__ unsigned hist[256];
    __shared__ unsigned sh_bin;
    __shared__ int sh_need;
    __shared__ int cntLess, cntEq;

    unsigned prefix = 0;
    int plen = 0;
    int need = CTX;

    for (int pass = 0; pass < 4; ++pass) {
        const int shift = 24 - 8 * pass;
        hist[tid] = 0;
        __syncthreads();
        for (int n = tid; n < N_CAND; n += 256) {
            const unsigned u = f2u_mono(srow[n]);
            if (plen == 0 || (u >> (32 - plen)) == prefix)
                atomicAdd(&hist[(u >> shift) & 255u], 1u);
        }
        __syncthreads();
        if (tid == 0) {
            int cum = 0;
            for (int bb = 0; bb < 256; ++bb) {
                const int h = (int)hist[bb];
                if (cum + h >= need) { sh_bin = (unsigned)bb; sh_need = need - cum; break; }
                cum += h;
            }
        }
        __syncthreads();
        prefix = (prefix << 8) | sh_bin;
        need = sh_need;
        plen += 8;
        __syncthreads();
    }

    const unsigned T = prefix;           // key of the 96th smallest
    const int numLess = CTX - need;      // strictly-less count
    if (tid == 0) { cntLess = 0; cntEq = 0; }
    __syncthreads();

    for (int n = tid; n < N_CAND; n += 256) {
        const float f = srow[n];
        const unsigned u = f2u_mono(f);
        if (u < T) {
            const int p = atomicAdd(&cntLess, 1);
            idx_out[row * CTX + p] = n;
            sval_out[row * CTX + p] = f;
        } else if (u == T) {
            const int p = atomicAdd(&cntEq, 1);
            if (p < need) {
                idx_out[row * CTX + numLess + p] = n;
                sval_out[row * CTX + numLess + p] = f;
            }
        }
    }
}

// ---------------------------------------------------------------------------
// Softmax over 96 context slots (probs = softmax(-s); the -||k||^2 per-row
// constant cancels). One block of 128 per row.
// ---------------------------------------------------------------------------
__global__ __launch_bounds__(128)
void softmax96_kernel(const float* __restrict__ sval, float* __restrict__ probs)
{
    __shared__ float sh[128];
    const int row = blockIdx.x, tid = threadIdx.x;
    const float v = (tid < CTX) ? -sval[row * CTX + tid] : -1e30f;
    sh[tid] = v;
    __syncthreads();
    for (int s = 64; s > 0; s >>= 1) {
        if (tid < s) sh[tid] = fmaxf(sh[tid], sh[tid + s]);
        __syncthreads();
    }
    const float m = sh[0];
    __syncthreads();
    const float e = (tid < CTX) ? __expf(v - m) : 0.f;
    sh[tid] = e;
    __syncthreads();
    for (int s = 64; s > 0; s >>= 1) {
        if (tid < s) sh[tid] += sh[tid + s];
        __syncthreads();
    }
    if (tid < CTX) probs[row * CTX + tid] = e / sh[0];
}

// ---------------------------------------------------------------------------
// diff[(b,c), d] = k_x[b,d] - cand_k[idx[b,c], d]   (b is chunk-local)
// ---------------------------------------------------------------------------
__global__ __launch_bounds__(256)
void build_diff_kernel(const float* __restrict__ k_x, const float* __restrict__ cand_k,
                       const int* __restrict__ idx, float* __restrict__ diff)
{
    const int bc = blockIdx.x;
    const int b = bc / CTX;
    const int d = threadIdx.x;
    const int id = idx[bc];
    diff[(size_t)bc * D_MAIN + d] =
        k_x[(size_t)b * D_MAIN + d] - cand_k[(size_t)id * D_MAIN + d];
}

// ---------------------------------------------------------------------------
// h[b,d] += sum_c probs[b,c] * (label_emb[cand_y[idx[b,c]], d] + v[(b,c), d])
// (b is chunk-local; h/v/probs/idx pointers pre-offset)
// ---------------------------------------------------------------------------
__global__ __launch_bounds__(256)
void mix_reduce_kernel(float* __restrict__ h, const float* __restrict__ v,
                       const float* __restrict__ probs, const int* __restrict__ idx,
                       const int* __restrict__ cy, const float* __restrict__ label_emb)
{
    const int b = blockIdx.x;
    const int d = threadIdx.x;
    float acc = 0.f;
    for (int c = 0; c < CTX; ++c) {
        const int bc = b * CTX + c;
        const int id = idx[bc];
        const int y = cy[id];
        const float val = label_emb[(size_t)y * D_MAIN + d] + v[(size_t)bc * D_MAIN + d];
        acc = fmaf(probs[bc], val, acc);
    }
    h[(size_t)b * D_MAIN + d] += acc;
}

// ---------------------------------------------------------------------------
// Host-side orchestration
// ---------------------------------------------------------------------------
static inline dim3 ggrid(int M, int N) {
    return dim3((unsigned)((N + 63) / 64), (unsigned)((M + 63) / 64));
}

static void encode_rows(const float* X, int R,
                        const float* W_lin, const float* b_lin,
                        const float* e0W1, const float* e0b1,
                        const float* e0W2, const float* e0b2,
                        const float* e1g, const float* e1b,
                        const float* e1W1, const float* e1b1,
                        const float* e1W2, const float* e1b2,
                        const float* mixg, const float* mixb,
                        const float* KW, const float* Kb,
                        float* H, float* T, float* TN, float* Kout,
                        hipStream_t stream)
{
    dim3 blk(256);
    gemm_nn<false, true, false><<<ggrid(R, D_MAIN), blk, 0, stream>>>(X, W_lin, b_lin, nullptr, H, R, D_MAIN, D_IN);
    gemm_nn<true,  true, false><<<ggrid(R, D_BLOCK), blk, 0, stream>>>(H, e0W1, e0b1, nullptr, T, R, D_BLOCK, D_MAIN);
    gemm_nn<false, true, true ><<<ggrid(R, D_MAIN), blk, 0, stream>>>(T, e0W2, e0b2, H, H, R, D_MAIN, D_BLOCK);
    ln_kernel<false><<<R, 256, 0, stream>>>(H, e1g, e1b, TN);
    gemm_nn<true,  true, false><<<ggrid(R, D_BLOCK), blk, 0, stream>>>(TN, e1W1, e1b1, nullptr, T, R, D_BLOCK, D_MAIN);
    gemm_nn<false, true, true ><<<ggrid(R, D_MAIN), blk, 0, stream>>>(T, e1W2, e1b2, H, H, R, D_MAIN, D_BLOCK);
    ln_kernel<false><<<R, 256, 0, stream>>>(H, mixg, mixb, TN);
    gemm_nn<false, true, false><<<ggrid(R, D_MAIN), blk, 0, stream>>>(TN, KW, Kb, nullptr, Kout, R, D_MAIN, D_MAIN);
}

extern "C" void kernel_launch(void* const* d_in, const int* in_sizes, int n_in,
                              void* d_out, int out_size, void* d_ws, size_t ws_size,
                              hipStream_t stream)
{
    const float* x        = (const float*)d_in[0];
    const float* cand_x   = (const float*)d_in[1];
    const int*   cand_y   = (const int*)  d_in[2];
    // d_in[3] = context_size (compile-time CTX=96)
    const float* W_lin    = (const float*)d_in[4];
    const float* b_lin    = (const float*)d_in[5];
    const float* e0W1     = (const float*)d_in[6];
    const float* e0b1     = (const float*)d_in[7];
    const float* e0W2     = (const float*)d_in[8];
    const float* e0b2     = (const float*)d_in[9];
    const float* e1g      = (const float*)d_in[10];
    const float* e1b      = (const float*)d_in[11];
    const float* e1W1     = (const float*)d_in[12];
    const float* e1b1     = (const float*)d_in[13];
    const float* e1W2     = (const float*)d_in[14];
    const float* e1b2     = (const float*)d_in[15];
    const float* mixg     = (const float*)d_in[16];
    const float* mixb     = (const float*)d_in[17];
    const float* K_W      = (const float*)d_in[18];
    const float* K_b      = (const float*)d_in[19];
    const float* label_emb= (const float*)d_in[20];
    const float* T_W1     = (const float*)d_in[21];
    const float* T_b1     = (const float*)d_in[22];
    const float* T_W2     = (const float*)d_in[23];
    const float* p0g      = (const float*)d_in[24];
    const float* p0b      = (const float*)d_in[25];
    const float* p0W1     = (const float*)d_in[26];
    const float* p0b1     = (const float*)d_in[27];
    const float* p0W2     = (const float*)d_in[28];
    const float* p0b2     = (const float*)d_in[29];
    const float* p1g      = (const float*)d_in[30];
    const float* p1b      = (const float*)d_in[31];
    const float* p1W1     = (const float*)d_in[32];
    const float* p1b1     = (const float*)d_in[33];
    const float* p1W2     = (const float*)d_in[34];
    const float* p1b2     = (const float*)d_in[35];
    const float* headg    = (const float*)d_in[36];
    const float* headb    = (const float*)d_in[37];
    const float* head_W   = (const float*)d_in[38];
    const float* head_bias= (const float*)d_in[39];

    // ---- workspace layout: ~84 MB total (chunked scratch pool) ----
    char* ws = (char*)d_ws;
    size_t off = 0;
    auto alloc = [&](size_t bytes) -> char* {
        char* p = ws + off;
        off += (bytes + 255) & ~(size_t)255;
        return p;
    };
    float* cand_k = (float*)alloc((size_t)N_CAND * D_MAIN * 4);     // 51.2 MB (persistent)
    float* ck2    = (float*)alloc((size_t)N_CAND * 4);              // 0.2 MB
    float* h_x    = (float*)alloc((size_t)B_ROWS * D_MAIN * 4);
    float* tn_x   = (float*)alloc((size_t)B_ROWS * D_MAIN * 4);
    float* t_x    = (float*)alloc((size_t)B_ROWS * D_BLOCK * 4);
    float* k_x    = (float*)alloc((size_t)B_ROWS * D_MAIN * 4);
    int*   idx    = (int*)  alloc((size_t)B_ROWS * CTX * 4);
    float* sval   = (float*)alloc((size_t)B_ROWS * CTX * 4);
    float* probs  = (float*)alloc((size_t)B_ROWS * CTX * 4);
    // shared pool: max(enc chunk 25.6MB, dist chunk 25.6MB, T-MLP chunk 18.9MB)
    const size_t POOL_BYTES = (size_t)RC_ENC * (D_MAIN + D_MAIN + D_BLOCK) * 4;
    char* pool = alloc(POOL_BYTES);

    dim3 blk(256);

    // 1) encode candidates -> cand_k  (8 chunks of 6250 rows)
    for (int c = 0; c < N_CAND / RC_ENC; ++c) {
        const int r0 = c * RC_ENC;
        float* Hc  = (float*)pool;
        float* TNc = Hc  + (size_t)RC_ENC * D_MAIN;
        float* Tc  = TNc + (size_t)RC_ENC * D_MAIN;
        encode_rows(cand_x + (size_t)r0 * D_IN, RC_ENC,
                    W_lin, b_lin, e0W1, e0b1, e0W2, e0b2,
                    e1g, e1b, e1W1, e1b1, e1W2, e1b2, mixg, mixb, K_W, K_b,
                    Hc, Tc, TNc, cand_k + (size_t)r0 * D_MAIN, stream);
    }

    // 2) encode x -> h_x, k_x
    encode_rows(x, B_ROWS, W_lin, b_lin, e0W1, e0b1, e0W2, e0b2,
                e1g, e1b, e1W1, e1b1, e1W2, e1b2, mixg, mixb, K_W, K_b,
                h_x, t_x, tn_x, k_x, stream);

    // 3) candidate squared norms
    cn2_kernel<<<N_CAND, 64, 0, stream>>>(cand_k, ck2);

    // 4+5) distances + exact top-96, in 8 chunks of 128 query rows
    for (int c = 0; c < B_ROWS / MB_CH; ++c) {
        const int m0 = c * MB_CH;
        float* s_c = (float*)pool;   // [128 x 50000]
        gemm_nt_dist<<<ggrid(MB_CH, N_CAND), blk, 0, stream>>>(
            k_x + (size_t)m0 * D_MAIN, cand_k, ck2, s_c, MB_CH, N_CAND, D_MAIN);
        topk96_kernel<<<MB_CH, 256, 0, stream>>>(s_c, idx + m0 * CTX, sval + m0 * CTX);
    }

    // 6) probs = softmax(-s)  (per-row -||k||^2 constant cancels)
    softmax96_kernel<<<B_ROWS, 128, 0, stream>>>(sval, probs);

    // 7-10) T-MLP + mix, in 16 chunks of 64 batch rows (6144 bc-rows each)
    for (int c = 0; c < B_ROWS / BB_CH; ++c) {
        const int b0 = c * BB_CH;
        const int R  = BB_CH * CTX;          // 6144
        float* diff = (float*)pool;          // [R x 256]; later reused as v
        float* t2   = diff + (size_t)R * D_MAIN;  // [R x 512]
        build_diff_kernel<<<R, 256, 0, stream>>>(
            k_x + (size_t)b0 * D_MAIN, cand_k, idx + b0 * CTX, diff);
        gemm_nn<true, true, false><<<ggrid(R, D_BLOCK), blk, 0, stream>>>(
            diff, T_W1, T_b1, nullptr, t2, R, D_BLOCK, D_MAIN);
        gemm_nn<false, false, false><<<ggrid(R, D_MAIN), blk, 0, stream>>>(
            t2, T_W2, nullptr, nullptr, diff, R, D_MAIN, D_BLOCK);   // v overwrites diff
        mix_reduce_kernel<<<BB_CH, 256, 0, stream>>>(
            h_x + (size_t)b0 * D_MAIN, diff, probs + b0 * CTX, idx + b0 * CTX,
            cand_y, label_emb);
    }

    // 11) post blocks p0, p1
    ln_kernel<false><<<B_ROWS, 256, 0, stream>>>(h_x, p0g, p0b, tn_x);
    gemm_nn<true,  true, false><<<ggrid(B_ROWS, D_BLOCK), blk, 0, stream>>>(tn_x, p0W1, p0b1, nullptr, t_x, B_ROWS, D_BLOCK, D_MAIN);
    gemm_nn<false, true, true ><<<ggrid(B_ROWS, D_MAIN), blk, 0, stream>>>(t_x, p0W2, p0b2, h_x, h_x, B_ROWS, D_MAIN, D_BLOCK);
    ln_kernel<false><<<B_ROWS, 256, 0, stream>>>(h_x, p1g, p1b, tn_x);
    gemm_nn<true,  true, false><<<ggrid(B_ROWS, D_BLOCK), blk, 0, stream>>>(tn_x, p1W1, p1b1, nullptr, t_x, B_ROWS, D_BLOCK, D_MAIN);
    gemm_nn<false, true, true ><<<ggrid(B_ROWS, D_MAIN), blk, 0, stream>>>(t_x, p1W2, p1b2, h_x, h_x, B_ROWS, D_MAIN, D_BLOCK);

    // 12) head: relu(ln(h)) @ head_W + head_bias
    ln_kernel<true><<<B_ROWS, 256, 0, stream>>>(h_x, headg, headb, tn_x);
    gemm_nn<false, true, false><<<ggrid(B_ROWS, N_OUT), blk, 0, stream>>>(
        tn_x, head_W, head_bias, nullptr, (float*)d_out, B_ROWS, N_OUT, D_MAIN);
}

// Round 3
// 3094.507 us; speedup vs baseline: 2.0650x; 2.0650x over previous
//
#include <hip/hip_runtime.h>
#include <cstdint>
#include <cstddef>

#define B_ROWS 1024
#define N_CAND 50000
#define CTX    96
#define D_IN   128
#define D_MAIN 256
#define D_BLOCK 512
#define N_OUT  10
#define LN_EPS 1e-5f

// ---------------------------------------------------------------------------
// 128x128 fp32 GEMM, BK=16, 256 threads, 8x8 micro-tile.
//   BT=false: B is [K x N] row-major.  BT=true: B is [N x K] row-major.
//   DIST: C = -2*acc + nb[n]   (nb = candidate squared norms)
//   else: C = act(acc + bias) (+ R)
// Requires K % 16 == 0, N % 8 == 0 (true for all uses: N in {256,512,50000}).
// ---------------------------------------------------------------------------
template<bool BT, bool RELU, bool HAS_BIAS, bool HAS_RES, bool DIST>
__global__ __launch_bounds__(256)
void gemm128(const float* __restrict__ A, const float* __restrict__ Bm,
             const float* __restrict__ bias, const float* __restrict__ Rm,
             float* __restrict__ C, int M, int N, int K)
{
    __shared__ float As[16][128];
    __shared__ float Bs[16][128];
    const int tid = threadIdx.x;
    const int bm = blockIdx.y * 128;
    const int bn = blockIdx.x * 128;

    const int ar = tid >> 1;          // 0..127 (row within tile for A / BT-B)
    const int ak = (tid & 1) << 3;    // 0 or 8  (k offset, 8 floats)
    const int kb = tid >> 4;          // 0..15   (k row for NN-B)
    const int nb0 = (tid & 15) << 3;  // 0..120  (n offset for NN-B)

    const int my = (tid >> 4) << 3;   // 0..120 row group
    const int nx = (tid & 15) << 3;   // 0..120 col group

    float acc[8][8] = {};

    for (int k0 = 0; k0 < K; k0 += 16) {
        // ---- stage A tile (transposed into As[k][m]) ----
        {
            float4 v0 = make_float4(0.f,0.f,0.f,0.f), v1 = v0;
            const int gm = bm + ar;
            if (gm < M) {
                const float* ap = A + (size_t)gm * K + k0 + ak;
                v0 = *(const float4*)ap;
                v1 = *(const float4*)(ap + 4);
            }
            As[ak+0][ar]=v0.x; As[ak+1][ar]=v0.y; As[ak+2][ar]=v0.z; As[ak+3][ar]=v0.w;
            As[ak+4][ar]=v1.x; As[ak+5][ar]=v1.y; As[ak+6][ar]=v1.z; As[ak+7][ar]=v1.w;
        }
        // ---- stage B tile ----
        if (!BT) {
            // B[k][n], contiguous in n; N % 128 == 0 for all NN uses
            const float* bp = Bm + (size_t)(k0 + kb) * N + bn + nb0;
            const float4 v0 = *(const float4*)bp;
            const float4 v1 = *(const float4*)(bp + 4);
            *(float4*)&Bs[kb][nb0]   = v0;
            *(float4*)&Bs[kb][nb0+4] = v1;
        } else {
            // B[n][k], contiguous in k; transpose into Bs[k][n]
            float4 v0 = make_float4(0.f,0.f,0.f,0.f), v1 = v0;
            const int gn = bn + ar;
            if (gn < N) {
                const float* bp = Bm + (size_t)gn * K + k0 + ak;
                v0 = *(const float4*)bp;
                v1 = *(const float4*)(bp + 4);
            }
            Bs[ak+0][ar]=v0.x; Bs[ak+1][ar]=v0.y; Bs[ak+2][ar]=v0.z; Bs[ak+3][ar]=v0.w;
            Bs[ak+4][ar]=v1.x; Bs[ak+5][ar]=v1.y; Bs[ak+6][ar]=v1.z; Bs[ak+7][ar]=v1.w;
        }
        __syncthreads();

        #pragma unroll
        for (int k = 0; k < 16; ++k) {
            float a[8], b[8];
            *(float4*)&a[0] = *(const float4*)&As[k][my];
            *(float4*)&a[4] = *(const float4*)&As[k][my+4];
            *(float4*)&b[0] = *(const float4*)&Bs[k][nx];
            *(float4*)&b[4] = *(const float4*)&Bs[k][nx+4];
            #pragma unroll
            for (int i = 0; i < 8; ++i)
                #pragma unroll
                for (int j = 0; j < 8; ++j)
                    acc[i][j] = fmaf(a[i], b[j], acc[i][j]);
        }
        __syncthreads();
    }

    // ---- epilogue ----
    #pragma unroll
    for (int i = 0; i < 8; ++i) {
        const int m = bm + my + i;
        if (m >= M) continue;
        #pragma unroll
        for (int j = 0; j < 8; j += 4) {
            const int n = bn + nx + j;
            if (n >= N) continue;   // n%4==0 && N%4==0 -> whole quad valid iff n<N
            float4 v = make_float4(acc[i][j], acc[i][j+1], acc[i][j+2], acc[i][j+3]);
            if (DIST) {
                const float4 q = *(const float4*)(bias + n);  // nb
                v.x = -2.f*v.x + q.x; v.y = -2.f*v.y + q.y;
                v.z = -2.f*v.z + q.z; v.w = -2.f*v.w + q.w;
            } else {
                if (HAS_BIAS) {
                    const float4 q = *(const float4*)(bias + n);
                    v.x += q.x; v.y += q.y; v.z += q.z; v.w += q.w;
                }
                if (RELU) {
                    v.x = fmaxf(v.x, 0.f); v.y = fmaxf(v.y, 0.f);
                    v.z = fmaxf(v.z, 0.f); v.w = fmaxf(v.w, 0.f);
                }
                if (HAS_RES) {
                    const float4 q = *(const float4*)(Rm + (size_t)m * N + n);
                    v.x += q.x; v.y += q.y; v.z += q.z; v.w += q.w;
                }
            }
            *(float4*)(C + (size_t)m * N + n) = v;
        }
    }
}

// ---------------------------------------------------------------------------
// Small-N fp32 GEMM (head only, N=10): 64x64 tile, 4x4 micro-tile.
// ---------------------------------------------------------------------------
template<bool RELU, bool HAS_BIAS, bool HAS_RES>
__global__ __launch_bounds__(256)
void gemm_nn(const float* __restrict__ A, const float* __restrict__ Bm,
             const float* __restrict__ bias, const float* __restrict__ Rm,
             float* __restrict__ C, int M, int N, int K)
{
    __shared__ float As[16][64];
    __shared__ float Bs[16][64];
    const int tid = threadIdx.x;
    const int bm = blockIdx.y * 64;
    const int bn = blockIdx.x * 64;

    const int a_m = tid >> 2;
    const int a_k = (tid & 3) << 2;
    const int b_k = tid >> 4;
    const int b_n = (tid & 15) << 2;
    const int my = (tid >> 4) << 2;
    const int nx = (tid & 15) << 2;

    float acc[4][4] = {};

    for (int k0 = 0; k0 < K; k0 += 16) {
        float4 av = make_float4(0.f,0.f,0.f,0.f);
        const int gm = bm + a_m;
        if (gm < M) av = *(const float4*)(A + (size_t)gm * K + k0 + a_k);
        As[a_k+0][a_m]=av.x; As[a_k+1][a_m]=av.y; As[a_k+2][a_m]=av.z; As[a_k+3][a_m]=av.w;

        float4 bv = make_float4(0.f,0.f,0.f,0.f);
        const int gn = bn + b_n;
        const float* bp = Bm + (size_t)(k0 + b_k) * N + gn;
        if (gn + 0 < N) bv.x = bp[0];
        if (gn + 1 < N) bv.y = bp[1];
        if (gn + 2 < N) bv.z = bp[2];
        if (gn + 3 < N) bv.w = bp[3];
        *(float4*)&Bs[b_k][b_n] = bv;

        __syncthreads();
        #pragma unroll
        for (int k = 0; k < 16; ++k) {
            const float4 a4 = *(const float4*)&As[k][my];
            const float4 b4 = *(const float4*)&Bs[k][nx];
            const float a[4] = {a4.x,a4.y,a4.z,a4.w};
            const float b[4] = {b4.x,b4.y,b4.z,b4.w};
            #pragma unroll
            for (int i = 0; i < 4; ++i)
                #pragma unroll
                for (int j = 0; j < 4; ++j)
                    acc[i][j] = fmaf(a[i], b[j], acc[i][j]);
        }
        __syncthreads();
    }

    #pragma unroll
    for (int i = 0; i < 4; ++i) {
        const int m = bm + my + i;
        if (m >= M) continue;
        #pragma unroll
        for (int j = 0; j < 4; ++j) {
            const int n = bn + nx + j;
            if (n >= N) continue;
            float v = acc[i][j];
            if (HAS_BIAS) v += bias[n];
            if (RELU)     v = fmaxf(v, 0.f);
            if (HAS_RES)  v += Rm[(size_t)m * N + n];
            C[(size_t)m * N + n] = v;
        }
    }
}

// ---------------------------------------------------------------------------
// LayerNorm over D_MAIN=256 columns, one block per row.
// ---------------------------------------------------------------------------
template<bool RELU>
__global__ __launch_bounds__(256)
void ln_kernel(const float* __restrict__ X, const float* __restrict__ g,
               const float* __restrict__ b, float* __restrict__ Y)
{
    const int row = blockIdx.x, tid = threadIdx.x;
    const float x = X[(size_t)row * D_MAIN + tid];
    __shared__ float red[4];
    const int lane = tid & 63, wid = tid >> 6;

    float s = x;
    #pragma unroll
    for (int off = 32; off; off >>= 1) s += __shfl_down(s, off, 64);
    if (lane == 0) red[wid] = s;
    __syncthreads();
    const float mean = (red[0] + red[1] + red[2] + red[3]) * (1.f / D_MAIN);
    __syncthreads();

    const float xm = x - mean;
    s = xm * xm;
    #pragma unroll
    for (int off = 32; off; off >>= 1) s += __shfl_down(s, off, 64);
    if (lane == 0) red[wid] = s;
    __syncthreads();
    const float var = (red[0] + red[1] + red[2] + red[3]) * (1.f / D_MAIN);

    float y = xm / sqrtf(var + LN_EPS) * g[tid] + b[tid];
    if (RELU) y = fmaxf(y, 0.f);
    Y[(size_t)row * D_MAIN + tid] = y;
}

// ---------------------------------------------------------------------------
// ||cand_k[n]||^2 — one wave per row.
// ---------------------------------------------------------------------------
__global__ __launch_bounds__(64)
void cn2_kernel(const float* __restrict__ ck, float* __restrict__ out)
{
    const int row = blockIdx.x, lane = threadIdx.x;
    const float4 v = *(const float4*)(ck + (size_t)row * D_MAIN + lane * 4);
    float s = v.x*v.x + v.y*v.y + v.z*v.z + v.w*v.w;
    #pragma unroll
    for (int off = 32; off; off >>= 1) s += __shfl_down(s, off, 64);
    if (lane == 0) out[row] = s;
}

// ---------------------------------------------------------------------------
// Exact top-96 smallest per row: 4-pass radix select, 1024 threads/row,
// float4 loads, 4 replicated LDS histograms, wave-parallel threshold scan.
// ---------------------------------------------------------------------------
__device__ __forceinline__ unsigned f2u_mono(float f) {
    unsigned u = __float_as_uint(f);
    return u ^ ((u & 0x80000000u) ? 0xFFFFFFFFu : 0x80000000u);
}

__global__ __launch_bounds__(1024)
void topk96_kernel(const float* __restrict__ S, int* __restrict__ idx_out,
                   float* __restrict__ sval_out)
{
    const int row = blockIdx.x;
    const float* srow = S + (size_t)row * N_CAND;
    const int tid = threadIdx.x;
    const int grp = tid >> 8;                 // 4 histogram replicas

    __shared__ unsigned hist[4][256];
    __shared__ unsigned sh_bin, sh_need;
    __shared__ int cntLess, cntEq;

    unsigned prefix = 0;
    int plen = 0;
    int need = CTX;

    for (int pass = 0; pass < 4; ++pass) {
        const int shift = 24 - 8 * pass;
        ((unsigned*)hist)[tid] = 0;           // 1024 == 4*256
        __syncthreads();

        for (int i = tid; i < N_CAND / 4; i += 1024) {
            const float4 f = ((const float4*)srow)[i];
            const float vf[4] = {f.x, f.y, f.z, f.w};
            #pragma unroll
            for (int e = 0; e < 4; ++e) {
                const unsigned u = f2u_mono(vf[e]);
                if (plen == 0 || (u >> (32 - plen)) == prefix)
                    atomicAdd(&hist[grp][(u >> shift) & 255u], 1u);
            }
        }
        __syncthreads();

        if (tid < 256)
            hist[0][tid] += hist[1][tid] + hist[2][tid] + hist[3][tid];
        __syncthreads();

        // wave 0: lane l owns bins 4l..4l+3; exclusive scan across lanes
        if (tid < 64) {
            const unsigned b0 = hist[0][tid*4+0], b1 = hist[0][tid*4+1],
                           b2 = hist[0][tid*4+2], b3 = hist[0][tid*4+3];
            const unsigned lsum = b0 + b1 + b2 + b3;
            unsigned pre = lsum;
            #pragma unroll
            for (int off = 1; off < 64; off <<= 1) {
                const unsigned t = __shfl_up(pre, off, 64);
                if (tid >= off) pre += t;
            }
            const unsigned excl = pre - lsum;
            const unsigned nd = (unsigned)need;
            if (excl < nd && excl + lsum >= nd) {
                unsigned bin, rem;
                if      (excl + b0 >= nd)           { bin = tid*4+0; rem = nd - excl; }
                else if (excl + b0 + b1 >= nd)      { bin = tid*4+1; rem = nd - excl - b0; }
                else if (excl + b0 + b1 + b2 >= nd) { bin = tid*4+2; rem = nd - excl - b0 - b1; }
                else                                { bin = tid*4+3; rem = nd - excl - b0 - b1 - b2; }
                sh_bin = bin; sh_need = rem;
            }
        }
        __syncthreads();
        prefix = (prefix << 8) | sh_bin;
        need = (int)sh_need;
        plen += 8;
        __syncthreads();
    }

    const unsigned T = prefix;            // exact key of the 96th smallest
    const int numLess = CTX - need;       // strictly-less count
    if (tid == 0) { cntLess = 0; cntEq = 0; }
    __syncthreads();

    for (int i = tid; i < N_CAND / 4; i += 1024) {
        const float4 f = ((const float4*)srow)[i];
        const float vf[4] = {f.x, f.y, f.z, f.w};
        #pragma unroll
        for (int e = 0; e < 4; ++e) {
            const unsigned u = f2u_mono(vf[e]);
            if (u < T) {
                const int p = atomicAdd(&cntLess, 1);
                idx_out[row * CTX + p] = i*4 + e;
                sval_out[row * CTX + p] = vf[e];
            } else if (u == T) {
                const int p = atomicAdd(&cntEq, 1);
                if (p < need) {
                    idx_out[row * CTX + numLess + p] = i*4 + e;
                    sval_out[row * CTX + numLess + p] = vf[e];
                }
            }
        }
    }
}

// ---------------------------------------------------------------------------
// Softmax over 96 context slots (probs = softmax(-s)).
// ---------------------------------------------------------------------------
__global__ __launch_bounds__(128)
void softmax96_kernel(const float* __restrict__ sval, float* __restrict__ probs)
{
    __shared__ float sh[128];
    const int row = blockIdx.x, tid = threadIdx.x;
    const float v = (tid < CTX) ? -sval[row * CTX + tid] : -1e30f;
    sh[tid] = v;
    __syncthreads();
    for (int s = 64; s > 0; s >>= 1) {
        if (tid < s) sh[tid] = fmaxf(sh[tid], sh[tid + s]);
        __syncthreads();
    }
    const float m = sh[0];
    __syncthreads();
    const float e = (tid < CTX) ? __expf(v - m) : 0.f;
    sh[tid] = e;
    __syncthreads();
    for (int s = 64; s > 0; s >>= 1) {
        if (tid < s) sh[tid] += sh[tid + s];
        __syncthreads();
    }
    if (tid < CTX) probs[row * CTX + tid] = e / sh[0];
}

// ---------------------------------------------------------------------------
// diff[(b,c), d] = k_x[b,d] - cand_k[idx[b,c], d]   (b chunk-local)
// ---------------------------------------------------------------------------
__global__ __launch_bounds__(256)
void build_diff_kernel(const float* __restrict__ k_x, const float* __restrict__ cand_k,
                       const int* __restrict__ idx, float* __restrict__ diff)
{
    const int bc = blockIdx.x;
    const int b = bc / CTX;
    const int d = threadIdx.x;
    const int id = idx[bc];
    diff[(size_t)bc * D_MAIN + d] =
        k_x[(size_t)b * D_MAIN + d] - cand_k[(size_t)id * D_MAIN + d];
}

// ---------------------------------------------------------------------------
// h[b,d] += sum_c probs[b,c] * (label_emb[cand_y[idx[b,c]], d] + v[(b,c), d])
// ---------------------------------------------------------------------------
__global__ __launch_bounds__(256)
void mix_reduce_kernel(float* __restrict__ h, const float* __restrict__ v,
                       const float* __restrict__ probs, const int* __restrict__ idx,
                       const int* __restrict__ cy, const float* __restrict__ label_emb)
{
    const int b = blockIdx.x;
    const int d = threadIdx.x;
    float acc = 0.f;
    for (int c = 0; c < CTX; ++c) {
        const int bc = b * CTX + c;
        const int id = idx[bc];
        const int y = cy[id];
        const float val = label_emb[(size_t)y * D_MAIN + d] + v[(size_t)bc * D_MAIN + d];
        acc = fmaf(probs[bc], val, acc);
    }
    h[(size_t)b * D_MAIN + d] += acc;
}

// ---------------------------------------------------------------------------
// Host-side orchestration
// ---------------------------------------------------------------------------
static inline dim3 g128(int M, int N) {
    return dim3((unsigned)((N + 127) / 128), (unsigned)((M + 127) / 128));
}

static void encode_rows(const float* X, int R,
                        const float* W_lin, const float* b_lin,
                        const float* e0W1, const float* e0b1,
                        const float* e0W2, const float* e0b2,
                        const float* e1g, const float* e1b,
                        const float* e1W1, const float* e1b1,
                        const float* e1W2, const float* e1b2,
                        const float* mixg, const float* mixb,
                        const float* KW, const float* Kb,
                        float* H, float* T, float* TN, float* Kout,
                        hipStream_t stream)
{
    dim3 blk(256);
    gemm128<false,false,true,false,false><<<g128(R, D_MAIN), blk, 0, stream>>>(X, W_lin, b_lin, nullptr, H, R, D_MAIN, D_IN);
    gemm128<false,true, true,false,false><<<g128(R, D_BLOCK), blk, 0, stream>>>(H, e0W1, e0b1, nullptr, T, R, D_BLOCK, D_MAIN);
    gemm128<false,false,true,true, false><<<g128(R, D_MAIN), blk, 0, stream>>>(T, e0W2, e0b2, H, H, R, D_MAIN, D_BLOCK);
    ln_kernel<false><<<R, 256, 0, stream>>>(H, e1g, e1b, TN);
    gemm128<false,true, true,false,false><<<g128(R, D_BLOCK), blk, 0, stream>>>(TN, e1W1, e1b1, nullptr, T, R, D_BLOCK, D_MAIN);
    gemm128<false,false,true,true, false><<<g128(R, D_MAIN), blk, 0, stream>>>(T, e1W2, e1b2, H, H, R, D_MAIN, D_BLOCK);
    ln_kernel<false><<<R, 256, 0, stream>>>(H, mixg, mixb, TN);
    gemm128<false,false,true,false,false><<<g128(R, D_MAIN), blk, 0, stream>>>(TN, KW, Kb, nullptr, Kout, R, D_MAIN, D_MAIN);
}

extern "C" void kernel_launch(void* const* d_in, const int* in_sizes, int n_in,
                              void* d_out, int out_size, void* d_ws, size_t ws_size,
                              hipStream_t stream)
{
    const float* x        = (const float*)d_in[0];
    const float* cand_x   = (const float*)d_in[1];
    const int*   cand_y   = (const int*)  d_in[2];
    const float* W_lin    = (const float*)d_in[4];
    const float* b_lin    = (const float*)d_in[5];
    const float* e0W1     = (const float*)d_in[6];
    const float* e0b1     = (const float*)d_in[7];
    const float* e0W2     = (const float*)d_in[8];
    const float* e0b2     = (const float*)d_in[9];
    const float* e1g      = (const float*)d_in[10];
    const float* e1b      = (const float*)d_in[11];
    const float* e1W1     = (const float*)d_in[12];
    const float* e1b1     = (const float*)d_in[13];
    const float* e1W2     = (const float*)d_in[14];
    const float* e1b2     = (const float*)d_in[15];
    const float* mixg     = (const float*)d_in[16];
    const float* mixb     = (const float*)d_in[17];
    const float* K_W      = (const float*)d_in[18];
    const float* K_b      = (const float*)d_in[19];
    const float* label_emb= (const float*)d_in[20];
    const float* T_W1     = (const float*)d_in[21];
    const float* T_b1     = (const float*)d_in[22];
    const float* T_W2     = (const float*)d_in[23];
    const float* p0g      = (const float*)d_in[24];
    const float* p0b      = (const float*)d_in[25];
    const float* p0W1     = (const float*)d_in[26];
    const float* p0b1     = (const float*)d_in[27];
    const float* p0W2     = (const float*)d_in[28];
    const float* p0b2     = (const float*)d_in[29];
    const float* p1g      = (const float*)d_in[30];
    const float* p1b      = (const float*)d_in[31];
    const float* p1W1     = (const float*)d_in[32];
    const float* p1b1     = (const float*)d_in[33];
    const float* p1W2     = (const float*)d_in[34];
    const float* p1b2     = (const float*)d_in[35];
    const float* headg    = (const float*)d_in[36];
    const float* headb    = (const float*)d_in[37];
    const float* head_W   = (const float*)d_in[38];
    const float* head_bias= (const float*)d_in[39];

    // ---- workspace: persistent ~58 MB + shared pool (adaptive in ws_size) ----
    char* ws = (char*)d_ws;
    size_t off = 0;
    auto alloc = [&](size_t bytes) -> char* {
        char* p = ws + off;
        off += (bytes + 255) & ~(size_t)255;
        return p;
    };
    float* cand_k = (float*)alloc((size_t)N_CAND * D_MAIN * 4);   // 51.2 MB persistent
    float* ck2    = (float*)alloc((size_t)N_CAND * 4);
    float* h_x    = (float*)alloc((size_t)B_ROWS * D_MAIN * 4);
    float* tn_x   = (float*)alloc((size_t)B_ROWS * D_MAIN * 4);
    float* t_x    = (float*)alloc((size_t)B_ROWS * D_BLOCK * 4);
    float* k_x    = (float*)alloc((size_t)B_ROWS * D_MAIN * 4);
    int*   idx    = (int*)  alloc((size_t)B_ROWS * CTX * 4);
    float* sval   = (float*)alloc((size_t)B_ROWS * CTX * 4);
    float* probs  = (float*)alloc((size_t)B_ROWS * CTX * 4);

    const size_t pool_avail = (ws_size > off) ? (ws_size - off) : 0;
    // chunk sizes from available pool; floors are the proven-safe R2 values
    int rc_enc = (int)(pool_avail / ((size_t)4 * (D_MAIN + D_MAIN + D_BLOCK)));
    if (rc_enc > 25000) rc_enc = 25000;
    if (rc_enc < 6250)  rc_enc = 6250;
    int mb_ch = (int)(pool_avail / ((size_t)4 * N_CAND));
    if (mb_ch > B_ROWS) mb_ch = B_ROWS;
    if (mb_ch < 128)    mb_ch = 128;
    int bb_ch = (int)(pool_avail / ((size_t)4 * CTX * (D_MAIN + D_BLOCK)));
    if (bb_ch > B_ROWS) bb_ch = B_ROWS;
    if (bb_ch < 64)     bb_ch = 64;

    char* pool = ws + off;
    dim3 blk(256);

    // 1) encode candidates -> cand_k
    for (int r0 = 0; r0 < N_CAND; r0 += rc_enc) {
        const int R = (N_CAND - r0 < rc_enc) ? (N_CAND - r0) : rc_enc;
        float* Hc  = (float*)pool;
        float* TNc = Hc  + (size_t)rc_enc * D_MAIN;
        float* Tc  = TNc + (size_t)rc_enc * D_MAIN;
        encode_rows(cand_x + (size_t)r0 * D_IN, R,
                    W_lin, b_lin, e0W1, e0b1, e0W2, e0b2,
                    e1g, e1b, e1W1, e1b1, e1W2, e1b2, mixg, mixb, K_W, K_b,
                    Hc, Tc, TNc, cand_k + (size_t)r0 * D_MAIN, stream);
    }

    // 2) encode x -> h_x, k_x
    encode_rows(x, B_ROWS, W_lin, b_lin, e0W1, e0b1, e0W2, e0b2,
                e1g, e1b, e1W1, e1b1, e1W2, e1b2, mixg, mixb, K_W, K_b,
                h_x, t_x, tn_x, k_x, stream);

    // 3) candidate squared norms
    cn2_kernel<<<N_CAND, 64, 0, stream>>>(cand_k, ck2);

    // 4+5) distances + exact top-96, chunked over query rows
    for (int m0 = 0; m0 < B_ROWS; m0 += mb_ch) {
        const int R = (B_ROWS - m0 < mb_ch) ? (B_ROWS - m0) : mb_ch;
        float* s_c = (float*)pool;
        gemm128<true,false,false,false,true><<<g128(R, N_CAND), blk, 0, stream>>>(
            k_x + (size_t)m0 * D_MAIN, cand_k, ck2, nullptr, s_c, R, N_CAND, D_MAIN);
        topk96_kernel<<<R, 1024, 0, stream>>>(s_c, idx + m0 * CTX, sval + m0 * CTX);
    }

    // 6) probs = softmax(-s)
    softmax96_kernel<<<B_ROWS, 128, 0, stream>>>(sval, probs);

    // 7-10) T-MLP + mix, chunked over batch rows
    for (int b0 = 0; b0 < B_ROWS; b0 += bb_ch) {
        const int rows = (B_ROWS - b0 < bb_ch) ? (B_ROWS - b0) : bb_ch;
        const int R = rows * CTX;
        float* diff = (float*)pool;                  // [R x 256], later v
        float* t2   = diff + (size_t)bb_ch * CTX * D_MAIN;  // [R x 512]
        build_diff_kernel<<<R, 256, 0, stream>>>(
            k_x + (size_t)b0 * D_MAIN, cand_k, idx + b0 * CTX, diff);
        gemm128<false,true, true, false,false><<<g128(R, D_BLOCK), blk, 0, stream>>>(
            diff, T_W1, T_b1, nullptr, t2, R, D_BLOCK, D_MAIN);
        gemm128<false,false,false,false,false><<<g128(R, D_MAIN), blk, 0, stream>>>(
            t2, T_W2, nullptr, nullptr, diff, R, D_MAIN, D_BLOCK);
        mix_reduce_kernel<<<rows, 256, 0, stream>>>(
            h_x + (size_t)b0 * D_MAIN, diff, probs + b0 * CTX, idx + b0 * CTX,
            cand_y, label_emb);
    }

    // 11) post blocks p0, p1
    ln_kernel<false><<<B_ROWS, 256, 0, stream>>>(h_x, p0g, p0b, tn_x);
    gemm128<false,true, true,false,false><<<g128(B_ROWS, D_BLOCK), blk, 0, stream>>>(tn_x, p0W1, p0b1, nullptr, t_x, B_ROWS, D_BLOCK, D_MAIN);
    gemm128<false,false,true,true, false><<<g128(B_ROWS, D_MAIN), blk, 0, stream>>>(t_x, p0W2, p0b2, h_x, h_x, B_ROWS, D_MAIN, D_BLOCK);
    ln_kernel<false><<<B_ROWS, 256, 0, stream>>>(h_x, p1g, p1b, tn_x);
    gemm128<false,true, true,false,false><<<g128(B_ROWS, D_BLOCK), blk, 0, stream>>>(tn_x, p1W1, p1b1, nullptr, t_x, B_ROWS, D_BLOCK, D_MAIN);
    gemm128<false,false,true,true, false><<<g128(B_ROWS, D_MAIN), blk, 0, stream>>>(t_x, p1W2, p1b2, h_x, h_x, B_ROWS, D_MAIN, D_BLOCK);

    // 12) head
    ln_kernel<true><<<B_ROWS, 256, 0, stream>>>(h_x, headg, headb, tn_x);
    gemm_nn<false, true, false><<<dim3(1, (B_ROWS + 63) / 64), blk, 0, stream>>>(
        tn_x, head_W, head_bias, nullptr, (float*)d_out, B_ROWS, N_OUT, D_MAIN);
}

// Round 6
// 2298.116 us; speedup vs baseline: 2.7806x; 1.3465x over previous
//
#include <hip/hip_runtime.h>
#include <hip/hip_bf16.h>
#include <cstdint>
#include <cstddef>

#define B_ROWS 1024
#define N_CAND 50000
#define CTX    96
#define D_IN   128
#define D_MAIN 256
#define D_BLOCK 512
#define N_OUT  10
#define LN_EPS 1e-5f

typedef unsigned short u16;
typedef __attribute__((ext_vector_type(8))) short bf16x8;
typedef __attribute__((ext_vector_type(4))) float f32x4;

__device__ __forceinline__ u16 bf16_bits(float f) {
    __hip_bfloat16 h = __float2bfloat16(f);
    return *reinterpret_cast<u16*>(&h);
}
__device__ __forceinline__ float bits_to_f32(u16 b) {
    unsigned u = ((unsigned)b) << 16;
    return __uint_as_float(u);
}
__device__ __forceinline__ void split_f32(float v, u16& h, u16& l) {
    h = bf16_bits(v);
    l = bf16_bits(v - bits_to_f32(h));
}

// async global->LDS 16B per lane (dest = wave-uniform base + lane*16)
__device__ __forceinline__ void load_lds_16B(const void* gp, void* lp) {
    __builtin_amdgcn_global_load_lds((const __attribute__((address_space(1))) void*)gp,
                                     (__attribute__((address_space(3))) void*)lp,
                                     16, 0, 0);
}

// ---------------------------------------------------------------------------
// Split-bf16 MFMA GEMM (NT): C = epilogue( A[MxK] @ B[NxK]^T ), fp32-quality.
// A = Ah+Al, B = Bh+Bl (bf16 hi/lo). acc += AhBh + AlBh + AhBl (3 MFMA).
// 128x128 tile, BK=32, 256 threads (2x2 waves of 64x64), 16x16x32 MFMA.
// DIST: C = -2*acc + bias[n]. Outputs: f32 (Cf) and/or split bf16 (Ch,Cl).
// K % 32 == 0 required.
// ---------------------------------------------------------------------------
template<bool RELU, bool HAS_BIAS, bool HAS_RES, bool DIST, bool OUT_F32, bool OUT_SPLIT>
__global__ __launch_bounds__(256)
void gemm_split_nt(const u16* __restrict__ Ah, const u16* __restrict__ Al,
                   const u16* __restrict__ Bh, const u16* __restrict__ Bl,
                   const float* __restrict__ bias, const float* __restrict__ Rm,
                   float* __restrict__ Cf, u16* __restrict__ Ch, u16* __restrict__ Cl,
                   int M, int N, int K)
{
    __shared__ __align__(16) u16 Ash[128][32];
    __shared__ __align__(16) u16 Asl[128][32];
    __shared__ __align__(16) u16 Bsh[128][32];
    __shared__ __align__(16) u16 Bsl[128][32];

    const int tid  = threadIdx.x;
    const int wave = tid >> 6, lane = tid & 63;
    const int bm = blockIdx.y * 128, bn = blockIdx.x * 128;
    const int wm = (wave >> 1) * 64, wn = (wave & 1) * 64;
    const int l16 = lane & 15, quad = lane >> 4;

    const int srow = lane >> 2;          // 0..15
    const int scol = (lane & 3) * 8;     // 0,8,16,24 (u16 elems)

    f32x4 acc[4][4];
    #pragma unroll
    for (int i = 0; i < 4; ++i)
        #pragma unroll
        for (int j = 0; j < 4; ++j)
            acc[i][j] = (f32x4){0.f, 0.f, 0.f, 0.f};

    for (int k0 = 0; k0 < K; k0 += 32) {
        const int r0 = wave * 16 + srow, r1 = r0 + 64;
        int ga0 = bm + r0; if (ga0 > M - 1) ga0 = M - 1;
        int ga1 = bm + r1; if (ga1 > M - 1) ga1 = M - 1;
        int gb0 = bn + r0; if (gb0 > N - 1) gb0 = N - 1;
        int gb1 = bn + r1; if (gb1 > N - 1) gb1 = N - 1;
        const size_t a0 = (size_t)ga0 * K + k0 + scol;
        const size_t a1 = (size_t)ga1 * K + k0 + scol;
        const size_t b0 = (size_t)gb0 * K + k0 + scol;
        const size_t b1 = (size_t)gb1 * K + k0 + scol;

        load_lds_16B(Ah + a0, &Ash[wave * 16][0]);
        load_lds_16B(Ah + a1, &Ash[64 + wave * 16][0]);
        load_lds_16B(Al + a0, &Asl[wave * 16][0]);
        load_lds_16B(Al + a1, &Asl[64 + wave * 16][0]);
        load_lds_16B(Bh + b0, &Bsh[wave * 16][0]);
        load_lds_16B(Bh + b1, &Bsh[64 + wave * 16][0]);
        load_lds_16B(Bl + b0, &Bsl[wave * 16][0]);
        load_lds_16B(Bl + b1, &Bsl[64 + wave * 16][0]);
        __syncthreads();

        bf16x8 ah[4], al[4], bh[4], bl[4];
        #pragma unroll
        for (int i = 0; i < 4; ++i) {
            ah[i] = *(const bf16x8*)&Ash[wm + i * 16 + l16][quad * 8];
            al[i] = *(const bf16x8*)&Asl[wm + i * 16 + l16][quad * 8];
        }
        #pragma unroll
        for (int j = 0; j < 4; ++j) {
            bh[j] = *(const bf16x8*)&Bsh[wn + j * 16 + l16][quad * 8];
            bl[j] = *(const bf16x8*)&Bsl[wn + j * 16 + l16][quad * 8];
        }

        #pragma unroll
        for (int i = 0; i < 4; ++i)
            #pragma unroll
            for (int j = 0; j < 4; ++j) {
                acc[i][j] = __builtin_amdgcn_mfma_f32_16x16x32_bf16(ah[i], bh[j], acc[i][j], 0, 0, 0);
                acc[i][j] = __builtin_amdgcn_mfma_f32_16x16x32_bf16(al[i], bh[j], acc[i][j], 0, 0, 0);
                acc[i][j] = __builtin_amdgcn_mfma_f32_16x16x32_bf16(ah[i], bl[j], acc[i][j], 0, 0, 0);
            }
        __syncthreads();
    }

    // epilogue: C/D layout col=lane&15 (N), row=quad*4+reg (M)
    #pragma unroll
    for (int j = 0; j < 4; ++j) {
        const int n = bn + wn + j * 16 + l16;
        if (n >= N) continue;
        float bv = 0.f;
        if (HAS_BIAS || DIST) bv = bias[n];
        #pragma unroll
        for (int i = 0; i < 4; ++i) {
            #pragma unroll
            for (int r = 0; r < 4; ++r) {
                const int m = bm + wm + i * 16 + quad * 4 + r;
                if (m >= M) continue;
                float v = acc[i][j][r];
                if (DIST) {
                    v = -2.f * v + bv;
                } else {
                    if (HAS_BIAS) v += bv;
                    if (RELU)     v = fmaxf(v, 0.f);
                    if (HAS_RES)  v += Rm[(size_t)m * N + n];
                }
                if (OUT_F32)  Cf[(size_t)m * N + n] = v;
                if (OUT_SPLIT) {
                    u16 h, l; split_f32(v, h, l);
                    Ch[(size_t)m * N + n] = h;
                    Cl[(size_t)m * N + n] = l;
                }
            }
        }
    }
}

// ---------------------------------------------------------------------------
// fp32 128x128 GEMM (post blocks): 8x8 micro-tile. B row-major [KxN].
// ---------------------------------------------------------------------------
template<bool RELU, bool HAS_BIAS, bool HAS_RES>
__global__ __launch_bounds__(256)
void gemm128(const float* __restrict__ A, const float* __restrict__ Bm,
             const float* __restrict__ bias, const float* __restrict__ Rm,
             float* __restrict__ C, int M, int N, int K)
{
    __shared__ float As[16][128];
    __shared__ float Bs[16][128];
    const int tid = threadIdx.x;
    const int bm = blockIdx.y * 128;
    const int bn = blockIdx.x * 128;

    const int ar = tid >> 1;
    const int ak = (tid & 1) << 3;
    const int kb = tid >> 4;
    const int nb0 = (tid & 15) << 3;
    const int my = (tid >> 4) << 3;
    const int nx = (tid & 15) << 3;

    float acc[8][8] = {};

    for (int k0 = 0; k0 < K; k0 += 16) {
        {
            float4 v0 = make_float4(0.f,0.f,0.f,0.f), v1 = v0;
            const int gm = bm + ar;
            if (gm < M) {
                const float* ap = A + (size_t)gm * K + k0 + ak;
                v0 = *(const float4*)ap;
                v1 = *(const float4*)(ap + 4);
            }
            As[ak+0][ar]=v0.x; As[ak+1][ar]=v0.y; As[ak+2][ar]=v0.z; As[ak+3][ar]=v0.w;
            As[ak+4][ar]=v1.x; As[ak+5][ar]=v1.y; As[ak+6][ar]=v1.z; As[ak+7][ar]=v1.w;
        }
        {
            const float* bp = Bm + (size_t)(k0 + kb) * N + bn + nb0;
            *(float4*)&Bs[kb][nb0]   = *(const float4*)bp;
            *(float4*)&Bs[kb][nb0+4] = *(const float4*)(bp + 4);
        }
        __syncthreads();

        #pragma unroll
        for (int k = 0; k < 16; ++k) {
            float a[8], b[8];
            *(float4*)&a[0] = *(const float4*)&As[k][my];
            *(float4*)&a[4] = *(const float4*)&As[k][my+4];
            *(float4*)&b[0] = *(const float4*)&Bs[k][nx];
            *(float4*)&b[4] = *(const float4*)&Bs[k][nx+4];
            #pragma unroll
            for (int i = 0; i < 8; ++i)
                #pragma unroll
                for (int j = 0; j < 8; ++j)
                    acc[i][j] = fmaf(a[i], b[j], acc[i][j]);
        }
        __syncthreads();
    }

    #pragma unroll
    for (int i = 0; i < 8; ++i) {
        const int m = bm + my + i;
        if (m >= M) continue;
        #pragma unroll
        for (int j = 0; j < 8; j += 4) {
            const int n = bn + nx + j;
            if (n >= N) continue;
            float4 v = make_float4(acc[i][j], acc[i][j+1], acc[i][j+2], acc[i][j+3]);
            if (HAS_BIAS) {
                const float4 q = *(const float4*)(bias + n);
                v.x += q.x; v.y += q.y; v.z += q.z; v.w += q.w;
            }
            if (RELU) {
                v.x = fmaxf(v.x, 0.f); v.y = fmaxf(v.y, 0.f);
                v.z = fmaxf(v.z, 0.f); v.w = fmaxf(v.w, 0.f);
            }
            if (HAS_RES) {
                const float4 q = *(const float4*)(Rm + (size_t)m * N + n);
                v.x += q.x; v.y += q.y; v.z += q.z; v.w += q.w;
            }
            *(float4*)(C + (size_t)m * N + n) = v;
        }
    }
}

// ---------------------------------------------------------------------------
// Small-N fp32 GEMM (head, N=10)
// ---------------------------------------------------------------------------
__global__ __launch_bounds__(256)
void gemm_head(const float* __restrict__ A, const float* __restrict__ Bm,
               const float* __restrict__ bias, float* __restrict__ C,
               int M, int N, int K)
{
    __shared__ float As[16][64];
    __shared__ float Bs[16][64];
    const int tid = threadIdx.x;
    const int bm = blockIdx.y * 64;

    const int a_m = tid >> 2;
    const int a_k = (tid & 3) << 2;
    const int b_k = tid >> 4;
    const int b_n = (tid & 15) << 2;
    const int my = (tid >> 4) << 2;
    const int nx = (tid & 15) << 2;

    float acc[4][4] = {};

    for (int k0 = 0; k0 < K; k0 += 16) {
        float4 av = make_float4(0.f,0.f,0.f,0.f);
        const int gm = bm + a_m;
        if (gm < M) av = *(const float4*)(A + (size_t)gm * K + k0 + a_k);
        As[a_k+0][a_m]=av.x; As[a_k+1][a_m]=av.y; As[a_k+2][a_m]=av.z; As[a_k+3][a_m]=av.w;

        float4 bv = make_float4(0.f,0.f,0.f,0.f);
        const float* bp = Bm + (size_t)(k0 + b_k) * N + b_n;
        if (b_n + 0 < N) bv.x = bp[0];
        if (b_n + 1 < N) bv.y = bp[1];
        if (b_n + 2 < N) bv.z = bp[2];
        if (b_n + 3 < N) bv.w = bp[3];
        *(float4*)&Bs[b_k][b_n] = bv;

        __syncthreads();
        #pragma unroll
        for (int k = 0; k < 16; ++k) {
            const float4 a4 = *(const float4*)&As[k][my];
            const float4 b4 = *(const float4*)&Bs[k][nx];
            const float a[4] = {a4.x,a4.y,a4.z,a4.w};
            const float b[4] = {b4.x,b4.y,b4.z,b4.w};
            #pragma unroll
            for (int i = 0; i < 4; ++i)
                #pragma unroll
                for (int j = 0; j < 4; ++j)
                    acc[i][j] = fmaf(a[i], b[j], acc[i][j]);
        }
        __syncthreads();
    }

    #pragma unroll
    for (int i = 0; i < 4; ++i) {
        const int m = bm + my + i;
        if (m >= M) continue;
        #pragma unroll
        for (int j = 0; j < 4; ++j) {
            const int n = nx + j;
            if (n >= N) continue;
            C[(size_t)m * N + n] = acc[i][j] + bias[n];
        }
    }
}

// ---------------------------------------------------------------------------
// LayerNorm over 256 cols; OUT_SPLIT -> (Yh,Yl) bf16 split, else Yf f32.
// ---------------------------------------------------------------------------
template<bool RELU, bool OUT_SPLIT>
__global__ __launch_bounds__(256)
void ln_kernel(const float* __restrict__ X, const float* __restrict__ g,
               const float* __restrict__ b, float* __restrict__ Yf,
               u16* __restrict__ Yh, u16* __restrict__ Yl)
{
    const int row = blockIdx.x, tid = threadIdx.x;
    const float x = X[(size_t)row * D_MAIN + tid];
    __shared__ float red[4];
    const int lane = tid & 63, wid = tid >> 6;

    float s = x;
    #pragma unroll
    for (int off = 32; off; off >>= 1) s += __shfl_down(s, off, 64);
    if (lane == 0) red[wid] = s;
    __syncthreads();
    const float mean = (red[0] + red[1] + red[2] + red[3]) * (1.f / D_MAIN);
    __syncthreads();

    const float xm = x - mean;
    s = xm * xm;
    #pragma unroll
    for (int off = 32; off; off >>= 1) s += __shfl_down(s, off, 64);
    if (lane == 0) red[wid] = s;
    __syncthreads();
    const float var = (red[0] + red[1] + red[2] + red[3]) * (1.f / D_MAIN);

    float y = xm / sqrtf(var + LN_EPS) * g[tid] + b[tid];
    if (RELU) y = fmaxf(y, 0.f);
    if (OUT_SPLIT) {
        u16 h, l; split_f32(y, h, l);
        Yh[(size_t)row * D_MAIN + tid] = h;
        Yl[(size_t)row * D_MAIN + tid] = l;
    } else {
        Yf[(size_t)row * D_MAIN + tid] = y;
    }
}

// ---------------------------------------------------------------------------
// ||cand_k[n]||^2
// ---------------------------------------------------------------------------
__global__ __launch_bounds__(64)
void cn2_kernel(const float* __restrict__ ck, float* __restrict__ out)
{
    const int row = blockIdx.x, lane = threadIdx.x;
    const float4 v = *(const float4*)(ck + (size_t)row * D_MAIN + lane * 4);
    float s = v.x*v.x + v.y*v.y + v.z*v.z + v.w*v.w;
    #pragma unroll
    for (int off = 32; off; off >>= 1) s += __shfl_down(s, off, 64);
    if (lane == 0) out[row] = s;
}

// ---------------------------------------------------------------------------
// conversions
// ---------------------------------------------------------------------------
__global__ __launch_bounds__(256)
void f32_to_split_kernel(const float* __restrict__ src, u16* __restrict__ hi,
                         u16* __restrict__ lo, int n)
{
    int i = blockIdx.x * 256 + threadIdx.x;
    if (i < n) {
        u16 h, l; split_f32(src[i], h, l);
        hi[i] = h; lo[i] = l;
    }
}

__global__ __launch_bounds__(256)
void transpose_split_kernel(const float* __restrict__ src, u16* __restrict__ dh,
                            u16* __restrict__ dl, int R, int C)  // [RxC]f32 -> [CxR] split
{
    int idx = blockIdx.x * 256 + threadIdx.x;
    if (idx < R * C) {
        const int r = idx / C, c = idx % C;
        u16 h, l; split_f32(src[idx], h, l);
        dh[(size_t)c * R + r] = h;
        dl[(size_t)c * R + r] = l;
    }
}

// ---------------------------------------------------------------------------
// Exact top-96 smallest per row (radix select; set is order-free).
// ---------------------------------------------------------------------------
__device__ __forceinline__ unsigned f2u_mono(float f) {
    unsigned u = __float_as_uint(f);
    return u ^ ((u & 0x80000000u) ? 0xFFFFFFFFu : 0x80000000u);
}

__global__ __launch_bounds__(1024)
void topk96_kernel(const float* __restrict__ S, int* __restrict__ idx_out)
{
    const int row = blockIdx.x;
    const float* srow = S + (size_t)row * N_CAND;
    const int tid = threadIdx.x;
    const int grp = tid >> 8;

    __shared__ unsigned hist[4][256];
    __shared__ unsigned sh_bin, sh_need;
    __shared__ int cntLess, cntEq;

    unsigned prefix = 0;
    int plen = 0;
    int need = CTX;

    for (int pass = 0; pass < 4; ++pass) {
        const int shift = 24 - 8 * pass;
        ((unsigned*)hist)[tid] = 0;
        __syncthreads();

        for (int i = tid; i < N_CAND / 4; i += 1024) {
            const float4 f = ((const float4*)srow)[i];
            const float vf[4] = {f.x, f.y, f.z, f.w};
            #pragma unroll
            for (int e = 0; e < 4; ++e) {
                const unsigned u = f2u_mono(vf[e]);
                if (plen == 0 || (u >> (32 - plen)) == prefix)
                    atomicAdd(&hist[grp][(u >> shift) & 255u], 1u);
            }
        }
        __syncthreads();

        if (tid < 256)
            hist[0][tid] += hist[1][tid] + hist[2][tid] + hist[3][tid];
        __syncthreads();

        if (tid < 64) {
            const unsigned b0 = hist[0][tid*4+0], b1 = hist[0][tid*4+1],
                           b2 = hist[0][tid*4+2], b3 = hist[0][tid*4+3];
            const unsigned lsum = b0 + b1 + b2 + b3;
            unsigned pre = lsum;
            #pragma unroll
            for (int off = 1; off < 64; off <<= 1) {
                const unsigned t = __shfl_up(pre, off, 64);
                if (tid >= off) pre += t;
            }
            const unsigned excl = pre - lsum;
            const unsigned nd = (unsigned)need;
            if (excl < nd && excl + lsum >= nd) {
                unsigned bin, rem;
                if      (excl + b0 >= nd)           { bin = tid*4+0; rem = nd - excl; }
                else if (excl + b0 + b1 >= nd)      { bin = tid*4+1; rem = nd - excl - b0; }
                else if (excl + b0 + b1 + b2 >= nd) { bin = tid*4+2; rem = nd - excl - b0 - b1; }
                else                                { bin = tid*4+3; rem = nd - excl - b0 - b1 - b2; }
                sh_bin = bin; sh_need = rem;
            }
        }
        __syncthreads();
        prefix = (prefix << 8) | sh_bin;
        need = (int)sh_need;
        plen += 8;
        __syncthreads();
    }

    const unsigned T = prefix;
    const int numLess = CTX - need;
    if (tid == 0) { cntLess = 0; cntEq = 0; }
    __syncthreads();

    for (int i = tid; i < N_CAND / 4; i += 1024) {
        const float4 f = ((const float4*)srow)[i];
        const float vf[4] = {f.x, f.y, f.z, f.w};
        #pragma unroll
        for (int e = 0; e < 4; ++e) {
            const unsigned u = f2u_mono(vf[e]);
            if (u < T) {
                const int p = atomicAdd(&cntLess, 1);
                idx_out[row * CTX + p] = i*4 + e;
            } else if (u == T) {
                const int p = atomicAdd(&cntEq, 1);
                if (p < need) idx_out[row * CTX + numLess + p] = i*4 + e;
            }
        }
    }
}

// ---------------------------------------------------------------------------
// Exact fp32 partial distance for the selected 96:
// sval[bc] = ||c||^2 - 2 * k_x[b].cand_k[idx[bc]]   (one wave per bc)
// ---------------------------------------------------------------------------
__global__ __launch_bounds__(256)
void sim_exact_kernel(const float* __restrict__ k_x, const float* __restrict__ cand_k,
                      const float* __restrict__ ck2, const int* __restrict__ idx,
                      float* __restrict__ sval)
{
    const int bc = blockIdx.x * 4 + (threadIdx.x >> 6);
    const int lane = threadIdx.x & 63;
    const int b = bc / CTX;
    const int id = idx[bc];
    const float4 kv = *(const float4*)(k_x + (size_t)b * D_MAIN + lane * 4);
    const float4 cv = *(const float4*)(cand_k + (size_t)id * D_MAIN + lane * 4);
    float s = kv.x*cv.x + kv.y*cv.y + kv.z*cv.z + kv.w*cv.w;
    #pragma unroll
    for (int off = 32; off; off >>= 1) s += __shfl_down(s, off, 64);
    if (lane == 0) sval[bc] = ck2[id] - 2.f * s;
}

// ---------------------------------------------------------------------------
// softmax over 96 slots (probs = softmax(-sval); per-row const cancels)
// ---------------------------------------------------------------------------
__global__ __launch_bounds__(128)
void softmax96_kernel(const float* __restrict__ sval, float* __restrict__ probs)
{
    __shared__ float sh[128];
    const int row = blockIdx.x, tid = threadIdx.x;
    const float v = (tid < CTX) ? -sval[row * CTX + tid] : -1e30f;
    sh[tid] = v;
    __syncthreads();
    for (int s = 64; s > 0; s >>= 1) {
        if (tid < s) sh[tid] = fmaxf(sh[tid], sh[tid + s]);
        __syncthreads();
    }
    const float m = sh[0];
    __syncthreads();
    const float e = (tid < CTX) ? __expf(v - m) : 0.f;
    sh[tid] = e;
    __syncthreads();
    for (int s = 64; s > 0; s >>= 1) {
        if (tid < s) sh[tid] += sh[tid + s];
        __syncthreads();
    }
    if (tid < CTX) probs[row * CTX + tid] = e / sh[0];
}

// ---------------------------------------------------------------------------
// diff split: dh/dl[(b,c),d] = split(k_x[b,d] - cand_k[idx[bc],d])
// ---------------------------------------------------------------------------
__global__ __launch_bounds__(256)
void build_diff_kernel(const float* __restrict__ k_x, const float* __restrict__ cand_k,
                       const int* __restrict__ idx, u16* __restrict__ dh,
                       u16* __restrict__ dl)
{
    const int bc = blockIdx.x;
    const int b = bc / CTX;
    const int d = threadIdx.x;
    const int id = idx[bc];
    const float v = k_x[(size_t)b * D_MAIN + d] - cand_k[(size_t)id * D_MAIN + d];
    u16 h, l; split_f32(v, h, l);
    dh[(size_t)bc * D_MAIN + d] = h;
    dl[(size_t)bc * D_MAIN + d] = l;
}

// ---------------------------------------------------------------------------
// h[b,d] += sum_c probs[b,c] * (label_emb[cand_y[idx[b,c]], d] + v[(b,c), d])
// ---------------------------------------------------------------------------
__global__ __launch_bounds__(256)
void mix_reduce_kernel(float* __restrict__ h, const float* __restrict__ v,
                       const float* __restrict__ probs, const int* __restrict__ idx,
                       const int* __restrict__ cy, const float* __restrict__ label_emb)
{
    const int b = blockIdx.x;
    const int d = threadIdx.x;
    float acc = 0.f;
    for (int c = 0; c < CTX; ++c) {
        const int bc = b * CTX + c;
        const int id = idx[bc];
        const int y = cy[id];
        const float val = label_emb[(size_t)y * D_MAIN + d] + v[(size_t)bc * D_MAIN + d];
        acc = fmaf(probs[bc], val, acc);
    }
    h[(size_t)b * D_MAIN + d] += acc;
}

// ---------------------------------------------------------------------------
// host-side orchestration
// ---------------------------------------------------------------------------
static inline dim3 g128(int M, int N) {
    return dim3((unsigned)((N + 127) / 128), (unsigned)((M + 127) / 128));
}

struct EncW {  // transposed split weights + fp32 biases/ln params
    const u16 *WlinTh, *WlinTl, *e0W1Th, *e0W1Tl, *e0W2Th, *e0W2Tl,
              *e1W1Th, *e1W1Tl, *e1W2Th, *e1W2Tl, *KWTh, *KWTl;
    const float *b_lin, *e0b1, *e0b2, *e1g, *e1b, *e1b1, *e1b2, *mixg, *mixb, *Kb;
};

// encode R rows (split inputs Xh/Xl) -> H f32, K f32 + K split
static void encode_rows_split(const u16* Xh, const u16* Xl, int R, const EncW& w,
                              float* H, u16* Hh, u16* Hl, u16* Th, u16* Tl,
                              u16* TNh, u16* TNl, float* Kf, u16* Kh, u16* Kl,
                              hipStream_t stream)
{
    dim3 blk(256);
    gemm_split_nt<false,true,false,false,true,true><<<g128(R, D_MAIN), blk, 0, stream>>>(
        Xh, Xl, w.WlinTh, w.WlinTl, w.b_lin, nullptr, H, Hh, Hl, R, D_MAIN, D_IN);
    gemm_split_nt<true,true,false,false,false,true><<<g128(R, D_BLOCK), blk, 0, stream>>>(
        Hh, Hl, w.e0W1Th, w.e0W1Tl, w.e0b1, nullptr, nullptr, Th, Tl, R, D_BLOCK, D_MAIN);
    gemm_split_nt<false,true,true,false,true,false><<<g128(R, D_MAIN), blk, 0, stream>>>(
        Th, Tl, w.e0W2Th, w.e0W2Tl, w.e0b2, H, H, nullptr, nullptr, R, D_MAIN, D_BLOCK);
    ln_kernel<false,true><<<R, 256, 0, stream>>>(H, w.e1g, w.e1b, nullptr, TNh, TNl);
    gemm_split_nt<true,true,false,false,false,true><<<g128(R, D_BLOCK), blk, 0, stream>>>(
        TNh, TNl, w.e1W1Th, w.e1W1Tl, w.e1b1, nullptr, nullptr, Th, Tl, R, D_BLOCK, D_MAIN);
    gemm_split_nt<false,true,true,false,true,false><<<g128(R, D_MAIN), blk, 0, stream>>>(
        Th, Tl, w.e1W2Th, w.e1W2Tl, w.e1b2, H, H, nullptr, nullptr, R, D_MAIN, D_BLOCK);
    ln_kernel<false,true><<<R, 256, 0, stream>>>(H, w.mixg, w.mixb, nullptr, TNh, TNl);
    gemm_split_nt<false,true,false,false,true,true><<<g128(R, D_MAIN), blk, 0, stream>>>(
        TNh, TNl, w.KWTh, w.KWTl, w.Kb, nullptr, Kf, Kh, Kl, R, D_MAIN, D_MAIN);
}

extern "C" void kernel_launch(void* const* d_in, const int* in_sizes, int n_in,
                              void* d_out, int out_size, void* d_ws, size_t ws_size,
                              hipStream_t stream)
{
    const float* x        = (const float*)d_in[0];
    const float* cand_x   = (const float*)d_in[1];
    const int*   cand_y   = (const int*)  d_in[2];
    const float* W_lin    = (const float*)d_in[4];
    const float* b_lin    = (const float*)d_in[5];
    const float* e0W1     = (const float*)d_in[6];
    const float* e0b1     = (const float*)d_in[7];
    const float* e0W2     = (const float*)d_in[8];
    const float* e0b2     = (const float*)d_in[9];
    const float* e1g      = (const float*)d_in[10];
    const float* e1b      = (const float*)d_in[11];
    const float* e1W1     = (const float*)d_in[12];
    const float* e1b1     = (const float*)d_in[13];
    const float* e1W2     = (const float*)d_in[14];
    const float* e1b2     = (const float*)d_in[15];
    const float* mixg     = (const float*)d_in[16];
    const float* mixb     = (const float*)d_in[17];
    const float* K_W      = (const float*)d_in[18];
    const float* K_b      = (const float*)d_in[19];
    const float* label_emb= (const float*)d_in[20];
    const float* T_W1     = (const float*)d_in[21];
    const float* T_b1     = (const float*)d_in[22];
    const float* T_W2     = (const float*)d_in[23];
    const float* p0g      = (const float*)d_in[24];
    const float* p0b      = (const float*)d_in[25];
    const float* p0W1     = (const float*)d_in[26];
    const float* p0b1     = (const float*)d_in[27];
    const float* p0W2     = (const float*)d_in[28];
    const float* p0b2     = (const float*)d_in[29];
    const float* p1g      = (const float*)d_in[30];
    const float* p1b      = (const float*)d_in[31];
    const float* p1W1     = (const float*)d_in[32];
    const float* p1b1     = (const float*)d_in[33];
    const float* p1W2     = (const float*)d_in[34];
    const float* p1b2     = (const float*)d_in[35];
    const float* headg    = (const float*)d_in[36];
    const float* headb    = (const float*)d_in[37];
    const float* head_W   = (const float*)d_in[38];
    const float* head_bias= (const float*)d_in[39];

    char* ws = (char*)d_ws;
    size_t off = 0;
    auto alloc = [&](size_t bytes) -> char* {
        char* p = ws + off;
        off += (bytes + 255) & ~(size_t)255;
        return p;
    };

    // persistent (~145 MB)
    float* cand_k  = (float*)alloc((size_t)N_CAND * D_MAIN * 4);
    u16* cand_k_h  = (u16*)alloc((size_t)N_CAND * D_MAIN * 2);
    u16* cand_k_l  = (u16*)alloc((size_t)N_CAND * D_MAIN * 2);
    u16* cand_x_h  = (u16*)alloc((size_t)N_CAND * D_IN * 2);
    u16* cand_x_l  = (u16*)alloc((size_t)N_CAND * D_IN * 2);
    u16* x_h       = (u16*)alloc((size_t)B_ROWS * D_IN * 2);
    u16* x_l       = (u16*)alloc((size_t)B_ROWS * D_IN * 2);
    float* ck2     = (float*)alloc((size_t)N_CAND * 4);
    float* h_x     = (float*)alloc((size_t)B_ROWS * D_MAIN * 4);
    float* tn_x    = (float*)alloc((size_t)B_ROWS * D_MAIN * 4);
    float* t_x     = (float*)alloc((size_t)B_ROWS * D_BLOCK * 4);
    float* k_x     = (float*)alloc((size_t)B_ROWS * D_MAIN * 4);
    u16* xe_Hh     = (u16*)alloc((size_t)B_ROWS * D_MAIN * 2);
    u16* xe_Hl     = (u16*)alloc((size_t)B_ROWS * D_MAIN * 2);
    u16* xe_Th     = (u16*)alloc((size_t)B_ROWS * D_BLOCK * 2);
    u16* xe_Tl     = (u16*)alloc((size_t)B_ROWS * D_BLOCK * 2);
    u16* xe_TNh    = (u16*)alloc((size_t)B_ROWS * D_MAIN * 2);
    u16* xe_TNl    = (u16*)alloc((size_t)B_ROWS * D_MAIN * 2);
    u16* k_x_h     = (u16*)alloc((size_t)B_ROWS * D_MAIN * 2);
    u16* k_x_l     = (u16*)alloc((size_t)B_ROWS * D_MAIN * 2);
    int*   idx     = (int*)  alloc((size_t)B_ROWS * CTX * 4);
    float* sval    = (float*)alloc((size_t)B_ROWS * CTX * 4);
    float* probs   = (float*)alloc((size_t)B_ROWS * CTX * 4);

    // transposed split weights (~3.6 MB)
    u16* WlinTh = (u16*)alloc((size_t)D_IN  * D_MAIN * 2);
    u16* WlinTl = (u16*)alloc((size_t)D_IN  * D_MAIN * 2);
    u16* e0W1Th = (u16*)alloc((size_t)D_MAIN* D_BLOCK * 2);
    u16* e0W1Tl = (u16*)alloc((size_t)D_MAIN* D_BLOCK * 2);
    u16* e0W2Th = (u16*)alloc((size_t)D_BLOCK*D_MAIN * 2);
    u16* e0W2Tl = (u16*)alloc((size_t)D_BLOCK*D_MAIN * 2);
    u16* e1W1Th = (u16*)alloc((size_t)D_MAIN* D_BLOCK * 2);
    u16* e1W1Tl = (u16*)alloc((size_t)D_MAIN* D_BLOCK * 2);
    u16* e1W2Th = (u16*)alloc((size_t)D_BLOCK*D_MAIN * 2);
    u16* e1W2Tl = (u16*)alloc((size_t)D_BLOCK*D_MAIN * 2);
    u16* KWTh   = (u16*)alloc((size_t)D_MAIN* D_MAIN * 2);
    u16* KWTl   = (u16*)alloc((size_t)D_MAIN* D_MAIN * 2);
    u16* TW1Th  = (u16*)alloc((size_t)D_MAIN* D_BLOCK * 2);
    u16* TW1Tl  = (u16*)alloc((size_t)D_MAIN* D_BLOCK * 2);
    u16* TW2Th  = (u16*)alloc((size_t)D_BLOCK*D_MAIN * 2);
    u16* TW2Tl  = (u16*)alloc((size_t)D_BLOCK*D_MAIN * 2);

    const size_t pool_avail = (ws_size > off) ? (ws_size - off) : 0;
    // encoder chunk: per row = 1024(Hf32) + 2*512(Hhl) + 2*1024(Thl) + 2*512(TNhl) = 5120 B
    int rc_enc = (int)(pool_avail / 5120);
    if (rc_enc > 25000) rc_enc = 25000;
    if (rc_enc < 6250)  rc_enc = 6250;
    int mb_ch = (int)(pool_avail / ((size_t)4 * N_CAND));
    if (mb_ch > B_ROWS) mb_ch = B_ROWS;
    if (mb_ch < 128)    mb_ch = 128;
    // T-MLP chunk: per b-row = 96*(2*2*256 diff + 2*2*512 t2 + 4*256 v) = 393216 B
    int bb_ch = (int)(pool_avail / 393216);
    if (bb_ch > B_ROWS) bb_ch = B_ROWS;
    if (bb_ch < 64)     bb_ch = 64;

    char* pool = ws + off;
    dim3 blk(256);

    // 0) input + weight conversions (split)
    {
        f32_to_split_kernel<<<(B_ROWS*D_IN + 255)/256, blk, 0, stream>>>(x, x_h, x_l, B_ROWS*D_IN);
        f32_to_split_kernel<<<(N_CAND*D_IN + 255)/256, blk, 0, stream>>>(cand_x, cand_x_h, cand_x_l, N_CAND*D_IN);
        auto tr = [&](const float* s, u16* dh, u16* dl, int R, int C) {
            transpose_split_kernel<<<(R*C + 255)/256, blk, 0, stream>>>(s, dh, dl, R, C);
        };
        tr(W_lin, WlinTh, WlinTl, D_IN,   D_MAIN);
        tr(e0W1,  e0W1Th, e0W1Tl, D_MAIN, D_BLOCK);
        tr(e0W2,  e0W2Th, e0W2Tl, D_BLOCK,D_MAIN);
        tr(e1W1,  e1W1Th, e1W1Tl, D_MAIN, D_BLOCK);
        tr(e1W2,  e1W2Th, e1W2Tl, D_BLOCK,D_MAIN);
        tr(K_W,   KWTh,   KWTl,   D_MAIN, D_MAIN);
        tr(T_W1,  TW1Th,  TW1Tl,  D_MAIN, D_BLOCK);
        tr(T_W2,  TW2Th,  TW2Tl,  D_BLOCK,D_MAIN);
    }

    EncW w = { WlinTh, WlinTl, e0W1Th, e0W1Tl, e0W2Th, e0W2Tl,
               e1W1Th, e1W1Tl, e1W2Th, e1W2Tl, KWTh, KWTl,
               b_lin, e0b1, e0b2, e1g, e1b, e1b1, e1b2, mixg, mixb, K_b };

    // 1) encode candidates -> cand_k f32 + split
    for (int r0 = 0; r0 < N_CAND; r0 += rc_enc) {
        const int R = (N_CAND - r0 < rc_enc) ? (N_CAND - r0) : rc_enc;
        char* p = pool;
        float* Hc = (float*)p;        p += (size_t)rc_enc * D_MAIN * 4;
        u16* Hh  = (u16*)p;           p += (size_t)rc_enc * D_MAIN * 2;
        u16* Hl  = (u16*)p;           p += (size_t)rc_enc * D_MAIN * 2;
        u16* Th  = (u16*)p;           p += (size_t)rc_enc * D_BLOCK * 2;
        u16* Tl  = (u16*)p;           p += (size_t)rc_enc * D_BLOCK * 2;
        u16* TNh = (u16*)p;           p += (size_t)rc_enc * D_MAIN * 2;
        u16* TNl = (u16*)p;
        encode_rows_split(cand_x_h + (size_t)r0 * D_IN, cand_x_l + (size_t)r0 * D_IN,
                          R, w, Hc, Hh, Hl, Th, Tl, TNh, TNl,
                          cand_k + (size_t)r0 * D_MAIN,
                          cand_k_h + (size_t)r0 * D_MAIN,
                          cand_k_l + (size_t)r0 * D_MAIN, stream);
    }

    // 2) encode x -> h_x f32, k_x f32 + split
    encode_rows_split(x_h, x_l, B_ROWS, w, h_x, xe_Hh, xe_Hl, xe_Th, xe_Tl,
                      xe_TNh, xe_TNl, k_x, k_x_h, k_x_l, stream);

    // 3) candidate norms (f32)
    cn2_kernel<<<N_CAND, 64, 0, stream>>>(cand_k, ck2);

    // 4+5) distances (split MFMA ~= fp32) + exact top-96
    for (int m0 = 0; m0 < B_ROWS; m0 += mb_ch) {
        const int R = (B_ROWS - m0 < mb_ch) ? (B_ROWS - m0) : mb_ch;
        float* s_c = (float*)pool;
        gemm_split_nt<false,false,false,true,true,false><<<g128(R, N_CAND), blk, 0, stream>>>(
            k_x_h + (size_t)m0 * D_MAIN, k_x_l + (size_t)m0 * D_MAIN,
            cand_k_h, cand_k_l, ck2, nullptr, s_c, nullptr, nullptr,
            R, N_CAND, D_MAIN);
        topk96_kernel<<<R, 1024, 0, stream>>>(s_c, idx + m0 * CTX);
    }

    // 5b) exact fp32 sval for the selected 96
    sim_exact_kernel<<<B_ROWS * CTX / 4, 256, 0, stream>>>(k_x, cand_k, ck2, idx, sval);

    // 6) softmax
    softmax96_kernel<<<B_ROWS, 128, 0, stream>>>(sval, probs);

    // 7-10) T-MLP (split MFMA) + mix
    for (int b0 = 0; b0 < B_ROWS; b0 += bb_ch) {
        const int rows = (B_ROWS - b0 < bb_ch) ? (B_ROWS - b0) : bb_ch;
        const int R = rows * CTX;
        char* p = pool;
        u16* dh = (u16*)p;  p += (size_t)bb_ch * CTX * D_MAIN * 2;
        u16* dl = (u16*)p;  p += (size_t)bb_ch * CTX * D_MAIN * 2;
        u16* th = (u16*)p;  p += (size_t)bb_ch * CTX * D_BLOCK * 2;
        u16* tl = (u16*)p;  p += (size_t)bb_ch * CTX * D_BLOCK * 2;
        float* v = (float*)p;
        build_diff_kernel<<<R, 256, 0, stream>>>(
            k_x + (size_t)b0 * D_MAIN, cand_k, idx + b0 * CTX, dh, dl);
        gemm_split_nt<true,true,false,false,false,true><<<g128(R, D_BLOCK), blk, 0, stream>>>(
            dh, dl, TW1Th, TW1Tl, T_b1, nullptr, nullptr, th, tl, R, D_BLOCK, D_MAIN);
        gemm_split_nt<false,false,false,false,true,false><<<g128(R, D_MAIN), blk, 0, stream>>>(
            th, tl, TW2Th, TW2Tl, nullptr, nullptr, v, nullptr, nullptr, R, D_MAIN, D_BLOCK);
        mix_reduce_kernel<<<rows, 256, 0, stream>>>(
            h_x + (size_t)b0 * D_MAIN, v, probs + b0 * CTX, idx + b0 * CTX,
            cand_y, label_emb);
    }

    // 11) post blocks (fp32)
    ln_kernel<false,false><<<B_ROWS, 256, 0, stream>>>(h_x, p0g, p0b, tn_x, nullptr, nullptr);
    gemm128<true, true,false><<<g128(B_ROWS, D_BLOCK), blk, 0, stream>>>(tn_x, p0W1, p0b1, nullptr, t_x, B_ROWS, D_BLOCK, D_MAIN);
    gemm128<false,true,true ><<<g128(B_ROWS, D_MAIN), blk, 0, stream>>>(t_x, p0W2, p0b2, h_x, h_x, B_ROWS, D_MAIN, D_BLOCK);
    ln_kernel<false,false><<<B_ROWS, 256, 0, stream>>>(h_x, p1g, p1b, tn_x, nullptr, nullptr);
    gemm128<true, true,false><<<g128(B_ROWS, D_BLOCK), blk, 0, stream>>>(tn_x, p1W1, p1b1, nullptr, t_x, B_ROWS, D_BLOCK, D_MAIN);
    gemm128<false,true,true ><<<g128(B_ROWS, D_MAIN), blk, 0, stream>>>(t_x, p1W2, p1b2, h_x, h_x, B_ROWS, D_MAIN, D_BLOCK);

    // 12) head (fp32)
    ln_kernel<true,false><<<B_ROWS, 256, 0, stream>>>(h_x, headg, headb, tn_x, nullptr, nullptr);
    gemm_head<<<dim3(1, (B_ROWS + 63) / 64), blk, 0, stream>>>(
        tn_x, head_W, head_bias, (float*)d_out, B_ROWS, N_OUT, D_MAIN);
}

// Round 7
// 2151.414 us; speedup vs baseline: 2.9702x; 1.0682x over previous
//
#include <hip/hip_runtime.h>
#include <hip/hip_bf16.h>
#include <cstdint>
#include <cstddef>

#define B_ROWS 1024
#define N_CAND 50000
#define CTX    96
#define D_IN   128
#define D_MAIN 256
#define D_BLOCK 512
#define N_OUT  10
#define LN_EPS 1e-5f
#define MAXTIE 4096

typedef unsigned short u16;
typedef __attribute__((ext_vector_type(8))) short bf16x8;
typedef __attribute__((ext_vector_type(4))) float f32x4;

__device__ __forceinline__ u16 bf16_bits(float f) {
    __hip_bfloat16 h = __float2bfloat16(f);
    return *reinterpret_cast<u16*>(&h);
}
__device__ __forceinline__ float bits_to_f32(u16 b) {
    unsigned u = ((unsigned)b) << 16;
    return __uint_as_float(u);
}
__device__ __forceinline__ void split_f32(float v, u16& h, u16& l) {
    h = bf16_bits(v);
    l = bf16_bits(v - bits_to_f32(h));
}
__device__ __forceinline__ unsigned f2u_mono(float f) {
    unsigned u = __float_as_uint(f);
    return u ^ ((u & 0x80000000u) ? 0xFFFFFFFFu : 0x80000000u);
}

// async global->LDS 16B per lane (dest = wave-uniform base + lane*16)
__device__ __forceinline__ void load_lds_16B(const void* gp, void* lp) {
    __builtin_amdgcn_global_load_lds((const __attribute__((address_space(1))) void*)gp,
                                     (__attribute__((address_space(3))) void*)lp,
                                     16, 0, 0);
}

// ---------------------------------------------------------------------------
// Split-bf16 MFMA GEMM (NT): C = epilogue( A[MxK] @ B[NxK]^T ), ~fp32 quality.
// A = Ah(+Al if A_LO), B = Bh+Bl. acc += AhBh (+AlBh) + AhBl.
// 128x128 tile, BK=32, 256 threads, 16x16x32 MFMA.
// KEY16: C -> u16 monotone key of (-2*acc + bias[n]) into Ch.
// Outputs: f32 (Cf), split (Ch,Cl), plain bf16 (Ch). K % 32 == 0.
// ---------------------------------------------------------------------------
template<bool RELU, bool HAS_BIAS, bool HAS_RES, bool KEY16,
         bool OUT_F32, bool OUT_SPLIT, bool OUT_B16, bool A_LO>
__global__ __launch_bounds__(256)
void gemm_split_nt(const u16* __restrict__ Ah, const u16* __restrict__ Al,
                   const u16* __restrict__ Bh, const u16* __restrict__ Bl,
                   const float* __restrict__ bias, const float* __restrict__ Rm,
                   float* __restrict__ Cf, u16* __restrict__ Ch, u16* __restrict__ Cl,
                   int M, int N, int K)
{
    __shared__ __align__(16) u16 Ash[128 * 32];
    __shared__ __align__(16) u16 Asl[A_LO ? 128 * 32 : 8];
    __shared__ __align__(16) u16 Bsh[128 * 32];
    __shared__ __align__(16) u16 Bsl[128 * 32];

    const int tid  = threadIdx.x;
    const int wave = tid >> 6, lane = tid & 63;
    const int bm = blockIdx.y * 128, bn = blockIdx.x * 128;
    const int wm = (wave >> 1) * 64, wn = (wave & 1) * 64;
    const int l16 = lane & 15, quad = lane >> 4;

    const int srow = lane >> 2;          // 0..15
    const int scol = (lane & 3) * 8;     // 0,8,16,24 (u16 elems)

    f32x4 acc[4][4];
    #pragma unroll
    for (int i = 0; i < 4; ++i)
        #pragma unroll
        for (int j = 0; j < 4; ++j)
            acc[i][j] = (f32x4){0.f, 0.f, 0.f, 0.f};

    for (int k0 = 0; k0 < K; k0 += 32) {
        const int r0 = wave * 16 + srow, r1 = r0 + 64;
        int ga0 = bm + r0; if (ga0 > M - 1) ga0 = M - 1;
        int ga1 = bm + r1; if (ga1 > M - 1) ga1 = M - 1;
        int gb0 = bn + r0; if (gb0 > N - 1) gb0 = N - 1;
        int gb1 = bn + r1; if (gb1 > N - 1) gb1 = N - 1;
        const size_t a0 = (size_t)ga0 * K + k0 + scol;
        const size_t a1 = (size_t)ga1 * K + k0 + scol;
        const size_t b0 = (size_t)gb0 * K + k0 + scol;
        const size_t b1 = (size_t)gb1 * K + k0 + scol;

        load_lds_16B(Ah + a0, &Ash[(wave * 16) * 32]);
        load_lds_16B(Ah + a1, &Ash[(64 + wave * 16) * 32]);
        if (A_LO) {
            load_lds_16B(Al + a0, &Asl[(wave * 16) * 32]);
            load_lds_16B(Al + a1, &Asl[(64 + wave * 16) * 32]);
        }
        load_lds_16B(Bh + b0, &Bsh[(wave * 16) * 32]);
        load_lds_16B(Bh + b1, &Bsh[(64 + wave * 16) * 32]);
        load_lds_16B(Bl + b0, &Bsl[(wave * 16) * 32]);
        load_lds_16B(Bl + b1, &Bsl[(64 + wave * 16) * 32]);
        __syncthreads();

        bf16x8 ah[4], al[4], bh[4], bl[4];
        #pragma unroll
        for (int i = 0; i < 4; ++i) {
            ah[i] = *(const bf16x8*)&Ash[(wm + i * 16 + l16) * 32 + quad * 8];
            if (A_LO) al[i] = *(const bf16x8*)&Asl[(wm + i * 16 + l16) * 32 + quad * 8];
        }
        #pragma unroll
        for (int j = 0; j < 4; ++j) {
            bh[j] = *(const bf16x8*)&Bsh[(wn + j * 16 + l16) * 32 + quad * 8];
            bl[j] = *(const bf16x8*)&Bsl[(wn + j * 16 + l16) * 32 + quad * 8];
        }

        #pragma unroll
        for (int i = 0; i < 4; ++i)
            #pragma unroll
            for (int j = 0; j < 4; ++j) {
                acc[i][j] = __builtin_amdgcn_mfma_f32_16x16x32_bf16(ah[i], bh[j], acc[i][j], 0, 0, 0);
                if (A_LO)
                    acc[i][j] = __builtin_amdgcn_mfma_f32_16x16x32_bf16(al[i], bh[j], acc[i][j], 0, 0, 0);
                acc[i][j] = __builtin_amdgcn_mfma_f32_16x16x32_bf16(ah[i], bl[j], acc[i][j], 0, 0, 0);
            }
        __syncthreads();
    }

    // epilogue: C/D layout col=lane&15 (N), row=quad*4+reg (M)
    #pragma unroll
    for (int j = 0; j < 4; ++j) {
        const int n = bn + wn + j * 16 + l16;
        if (n >= N) continue;
        float bv = 0.f;
        if (HAS_BIAS || KEY16) bv = bias[n];
        #pragma unroll
        for (int i = 0; i < 4; ++i) {
            #pragma unroll
            for (int r = 0; r < 4; ++r) {
                const int m = bm + wm + i * 16 + quad * 4 + r;
                if (m >= M) continue;
                float v = acc[i][j][r];
                if (KEY16) {
                    v = -2.f * v + bv;
                    Ch[(size_t)m * N + n] = (u16)(f2u_mono(v) >> 16);
                } else {
                    if (HAS_BIAS) v += bv;
                    if (RELU)     v = fmaxf(v, 0.f);
                    if (HAS_RES)  v += Rm[(size_t)m * N + n];
                    if (OUT_F32)  Cf[(size_t)m * N + n] = v;
                    if (OUT_SPLIT) {
                        u16 h, l; split_f32(v, h, l);
                        Ch[(size_t)m * N + n] = h;
                        Cl[(size_t)m * N + n] = l;
                    }
                    if (OUT_B16) Ch[(size_t)m * N + n] = bf16_bits(v);
                }
            }
        }
    }
}

// ---------------------------------------------------------------------------
// fp32 128x128 GEMM (post blocks): 8x8 micro-tile. B row-major [KxN].
// ---------------------------------------------------------------------------
template<bool RELU, bool HAS_BIAS, bool HAS_RES>
__global__ __launch_bounds__(256)
void gemm128(const float* __restrict__ A, const float* __restrict__ Bm,
             const float* __restrict__ bias, const float* __restrict__ Rm,
             float* __restrict__ C, int M, int N, int K)
{
    __shared__ float As[16][128];
    __shared__ float Bs[16][128];
    const int tid = threadIdx.x;
    const int bm = blockIdx.y * 128;
    const int bn = blockIdx.x * 128;

    const int ar = tid >> 1;
    const int ak = (tid & 1) << 3;
    const int kb = tid >> 4;
    const int nb0 = (tid & 15) << 3;
    const int my = (tid >> 4) << 3;
    const int nx = (tid & 15) << 3;

    float acc[8][8] = {};

    for (int k0 = 0; k0 < K; k0 += 16) {
        {
            float4 v0 = make_float4(0.f,0.f,0.f,0.f), v1 = v0;
            const int gm = bm + ar;
            if (gm < M) {
                const float* ap = A + (size_t)gm * K + k0 + ak;
                v0 = *(const float4*)ap;
                v1 = *(const float4*)(ap + 4);
            }
            As[ak+0][ar]=v0.x; As[ak+1][ar]=v0.y; As[ak+2][ar]=v0.z; As[ak+3][ar]=v0.w;
            As[ak+4][ar]=v1.x; As[ak+5][ar]=v1.y; As[ak+6][ar]=v1.z; As[ak+7][ar]=v1.w;
        }
        {
            const float* bp = Bm + (size_t)(k0 + kb) * N + bn + nb0;
            *(float4*)&Bs[kb][nb0]   = *(const float4*)bp;
            *(float4*)&Bs[kb][nb0+4] = *(const float4*)(bp + 4);
        }
        __syncthreads();

        #pragma unroll
        for (int k = 0; k < 16; ++k) {
            float a[8], b[8];
            *(float4*)&a[0] = *(const float4*)&As[k][my];
            *(float4*)&a[4] = *(const float4*)&As[k][my+4];
            *(float4*)&b[0] = *(const float4*)&Bs[k][nx];
            *(float4*)&b[4] = *(const float4*)&Bs[k][nx+4];
            #pragma unroll
            for (int i = 0; i < 8; ++i)
                #pragma unroll
                for (int j = 0; j < 8; ++j)
                    acc[i][j] = fmaf(a[i], b[j], acc[i][j]);
        }
        __syncthreads();
    }

    #pragma unroll
    for (int i = 0; i < 8; ++i) {
        const int m = bm + my + i;
        if (m >= M) continue;
        #pragma unroll
        for (int j = 0; j < 8; j += 4) {
            const int n = bn + nx + j;
            if (n >= N) continue;
            float4 v = make_float4(acc[i][j], acc[i][j+1], acc[i][j+2], acc[i][j+3]);
            if (HAS_BIAS) {
                const float4 q = *(const float4*)(bias + n);
                v.x += q.x; v.y += q.y; v.z += q.z; v.w += q.w;
            }
            if (RELU) {
                v.x = fmaxf(v.x, 0.f); v.y = fmaxf(v.y, 0.f);
                v.z = fmaxf(v.z, 0.f); v.w = fmaxf(v.w, 0.f);
            }
            if (HAS_RES) {
                const float4 q = *(const float4*)(Rm + (size_t)m * N + n);
                v.x += q.x; v.y += q.y; v.z += q.z; v.w += q.w;
            }
            *(float4*)(C + (size_t)m * N + n) = v;
        }
    }
}

// ---------------------------------------------------------------------------
// Small-N fp32 GEMM (head, N=10)
// ---------------------------------------------------------------------------
__global__ __launch_bounds__(256)
void gemm_head(const float* __restrict__ A, const float* __restrict__ Bm,
               const float* __restrict__ bias, float* __restrict__ C,
               int M, int N, int K)
{
    __shared__ float As[16][64];
    __shared__ float Bs[16][64];
    const int tid = threadIdx.x;
    const int bm = blockIdx.y * 64;

    const int a_m = tid >> 2;
    const int a_k = (tid & 3) << 2;
    const int b_k = tid >> 4;
    const int b_n = (tid & 15) << 2;
    const int my = (tid >> 4) << 2;
    const int nx = (tid & 15) << 2;

    float acc[4][4] = {};

    for (int k0 = 0; k0 < K; k0 += 16) {
        float4 av = make_float4(0.f,0.f,0.f,0.f);
        const int gm = bm + a_m;
        if (gm < M) av = *(const float4*)(A + (size_t)gm * K + k0 + a_k);
        As[a_k+0][a_m]=av.x; As[a_k+1][a_m]=av.y; As[a_k+2][a_m]=av.z; As[a_k+3][a_m]=av.w;

        float4 bv = make_float4(0.f,0.f,0.f,0.f);
        const float* bp = Bm + (size_t)(k0 + b_k) * N + b_n;
        if (b_n + 0 < N) bv.x = bp[0];
        if (b_n + 1 < N) bv.y = bp[1];
        if (b_n + 2 < N) bv.z = bp[2];
        if (b_n + 3 < N) bv.w = bp[3];
        *(float4*)&Bs[b_k][b_n] = bv;

        __syncthreads();
        #pragma unroll
        for (int k = 0; k < 16; ++k) {
            const float4 a4 = *(const float4*)&As[k][my];
            const float4 b4 = *(const float4*)&Bs[k][nx];
            const float a[4] = {a4.x,a4.y,a4.z,a4.w};
            const float b[4] = {b4.x,b4.y,b4.z,b4.w};
            #pragma unroll
            for (int i = 0; i < 4; ++i)
                #pragma unroll
                for (int j = 0; j < 4; ++j)
                    acc[i][j] = fmaf(a[i], b[j], acc[i][j]);
        }
        __syncthreads();
    }

    #pragma unroll
    for (int i = 0; i < 4; ++i) {
        const int m = bm + my + i;
        if (m >= M) continue;
        #pragma unroll
        for (int j = 0; j < 4; ++j) {
            const int n = nx + j;
            if (n >= N) continue;
            C[(size_t)m * N + n] = acc[i][j] + bias[n];
        }
    }
}

// ---------------------------------------------------------------------------
// LayerNorm over 256 cols; OUT_SPLIT -> (Yh,Yl) bf16 split, else Yf f32.
// ---------------------------------------------------------------------------
template<bool RELU, bool OUT_SPLIT>
__global__ __launch_bounds__(256)
void ln_kernel(const float* __restrict__ X, const float* __restrict__ g,
               const float* __restrict__ b, float* __restrict__ Yf,
               u16* __restrict__ Yh, u16* __restrict__ Yl)
{
    const int row = blockIdx.x, tid = threadIdx.x;
    const float x = X[(size_t)row * D_MAIN + tid];
    __shared__ float red[4];
    const int lane = tid & 63, wid = tid >> 6;

    float s = x;
    #pragma unroll
    for (int off = 32; off; off >>= 1) s += __shfl_down(s, off, 64);
    if (lane == 0) red[wid] = s;
    __syncthreads();
    const float mean = (red[0] + red[1] + red[2] + red[3]) * (1.f / D_MAIN);
    __syncthreads();

    const float xm = x - mean;
    s = xm * xm;
    #pragma unroll
    for (int off = 32; off; off >>= 1) s += __shfl_down(s, off, 64);
    if (lane == 0) red[wid] = s;
    __syncthreads();
    const float var = (red[0] + red[1] + red[2] + red[3]) * (1.f / D_MAIN);

    float y = xm / sqrtf(var + LN_EPS) * g[tid] + b[tid];
    if (RELU) y = fmaxf(y, 0.f);
    if (OUT_SPLIT) {
        u16 h, l; split_f32(y, h, l);
        Yh[(size_t)row * D_MAIN + tid] = h;
        Yl[(size_t)row * D_MAIN + tid] = l;
    } else {
        Yf[(size_t)row * D_MAIN + tid] = y;
    }
}

// ---------------------------------------------------------------------------
// ||cand_k[n]||^2
// ---------------------------------------------------------------------------
__global__ __launch_bounds__(64)
void cn2_kernel(const float* __restrict__ ck, float* __restrict__ out)
{
    const int row = blockIdx.x, lane = threadIdx.x;
    const float4 v = *(const float4*)(ck + (size_t)row * D_MAIN + lane * 4);
    float s = v.x*v.x + v.y*v.y + v.z*v.z + v.w*v.w;
    #pragma unroll
    for (int off = 32; off; off >>= 1) s += __shfl_down(s, off, 64);
    if (lane == 0) out[row] = s;
}

// ---------------------------------------------------------------------------
// conversions
// ---------------------------------------------------------------------------
__global__ __launch_bounds__(256)
void f32_to_split_kernel(const float* __restrict__ src, u16* __restrict__ hi,
                         u16* __restrict__ lo, int n)
{
    int i = blockIdx.x * 256 + threadIdx.x;
    if (i < n) {
        u16 h, l; split_f32(src[i], h, l);
        hi[i] = h; lo[i] = l;
    }
}

__global__ __launch_bounds__(256)
void transpose_split_kernel(const float* __restrict__ src, u16* __restrict__ dh,
                            u16* __restrict__ dl, int R, int C)
{
    int idx = blockIdx.x * 256 + threadIdx.x;
    if (idx < R * C) {
        const int r = idx / C, c = idx % C;
        u16 h, l; split_f32(src[idx], h, l);
        dh[(size_t)c * R + r] = h;
        dl[(size_t)c * R + r] = l;
    }
}

// ---------------------------------------------------------------------------
// Top-96 smallest per row on u16 monotone keys: 2 histogram passes + collect.
// Equal-key candidates go to tiebuf for exact fp32 tie-break.
// ---------------------------------------------------------------------------
__global__ __launch_bounds__(1024)
void topk96_u16_kernel(const u16* __restrict__ keys, int* __restrict__ idx_out,
                       int* __restrict__ tiebuf, int* __restrict__ tiecnt,
                       int* __restrict__ lesscnt)
{
    const int row = blockIdx.x;
    const u16* krow = keys + (size_t)row * N_CAND;
    const int tid = threadIdx.x;
    const int grp = tid >> 7;                 // 8 histogram replicas

    __shared__ unsigned hist[8][256];
    __shared__ unsigned sh_bin, sh_need;
    __shared__ int cntLess, cntEq;

    // ---- pass 1: high byte ----
    hist[0][tid & 2047 ? 0 : 0] = 0;  // (placeholder to avoid unused warning)
    ((unsigned*)hist)[tid] = 0;
    ((unsigned*)hist)[tid + 1024] = 0;
    __syncthreads();
    for (int i = tid; i < N_CAND / 8; i += 1024) {
        const uint4 v = ((const uint4*)krow)[i];
        const unsigned w[4] = {v.x, v.y, v.z, v.w};
        #pragma unroll
        for (int e = 0; e < 4; ++e) {
            atomicAdd(&hist[grp][(w[e] & 0xFFFFu) >> 8], 1u);
            atomicAdd(&hist[grp][(w[e] >> 16) >> 8], 1u);
        }
    }
    __syncthreads();
    if (tid < 256) {
        unsigned s = hist[0][tid];
        #pragma unroll
        for (int r = 1; r < 8; ++r) s += hist[r][tid];
        hist[0][tid] = s;
    }
    __syncthreads();
    int need = CTX;
    if (tid < 64) {
        const unsigned b0 = hist[0][tid*4+0], b1 = hist[0][tid*4+1],
                       b2 = hist[0][tid*4+2], b3 = hist[0][tid*4+3];
        const unsigned lsum = b0 + b1 + b2 + b3;
        unsigned pre = lsum;
        #pragma unroll
        for (int off = 1; off < 64; off <<= 1) {
            const unsigned t = __shfl_up(pre, off, 64);
            if (tid >= off) pre += t;
        }
        const unsigned excl = pre - lsum;
        const unsigned nd = (unsigned)need;
        if (excl < nd && excl + lsum >= nd) {
            unsigned bin, rem;
            if      (excl + b0 >= nd)           { bin = tid*4+0; rem = nd - excl; }
            else if (excl + b0 + b1 >= nd)      { bin = tid*4+1; rem = nd - excl - b0; }
            else if (excl + b0 + b1 + b2 >= nd) { bin = tid*4+2; rem = nd - excl - b0 - b1; }
            else                                { bin = tid*4+3; rem = nd - excl - b0 - b1 - b2; }
            sh_bin = bin; sh_need = rem;
        }
    }
    __syncthreads();
    const unsigned hb = sh_bin;
    need = (int)sh_need;
    __syncthreads();

    // ---- pass 2: low byte among hb ----
    ((unsigned*)hist)[tid] = 0;
    ((unsigned*)hist)[tid + 1024] = 0;
    __syncthreads();
    for (int i = tid; i < N_CAND / 8; i += 1024) {
        const uint4 v = ((const uint4*)krow)[i];
        const unsigned w[4] = {v.x, v.y, v.z, v.w};
        #pragma unroll
        for (int e = 0; e < 4; ++e) {
            const unsigned k0 = w[e] & 0xFFFFu, k1 = w[e] >> 16;
            if ((k0 >> 8) == hb) atomicAdd(&hist[grp][k0 & 255u], 1u);
            if ((k1 >> 8) == hb) atomicAdd(&hist[grp][k1 & 255u], 1u);
        }
    }
    __syncthreads();
    if (tid < 256) {
        unsigned s = hist[0][tid];
        #pragma unroll
        for (int r = 1; r < 8; ++r) s += hist[r][tid];
        hist[0][tid] = s;
    }
    __syncthreads();
    if (tid < 64) {
        const unsigned b0 = hist[0][tid*4+0], b1 = hist[0][tid*4+1],
                       b2 = hist[0][tid*4+2], b3 = hist[0][tid*4+3];
        const unsigned lsum = b0 + b1 + b2 + b3;
        unsigned pre = lsum;
        #pragma unroll
        for (int off = 1; off < 64; off <<= 1) {
            const unsigned t = __shfl_up(pre, off, 64);
            if (tid >= off) pre += t;
        }
        const unsigned excl = pre - lsum;
        const unsigned nd = (unsigned)need;
        if (excl < nd && excl + lsum >= nd) {
            unsigned bin, rem;
            if      (excl + b0 >= nd)           { bin = tid*4+0; rem = nd - excl; }
            else if (excl + b0 + b1 >= nd)      { bin = tid*4+1; rem = nd - excl - b0; }
            else if (excl + b0 + b1 + b2 >= nd) { bin = tid*4+2; rem = nd - excl - b0 - b1; }
            else                                { bin = tid*4+3; rem = nd - excl - b0 - b1 - b2; }
            sh_bin = bin; sh_need = rem;
        }
    }
    __syncthreads();
    const unsigned T16 = (hb << 8) | sh_bin;
    need = (int)sh_need;                     // ties still needed from the == bin

    if (tid == 0) { cntLess = 0; cntEq = 0; }
    __syncthreads();

    // ---- pass 3: collect strictly-less, buffer ties ----
    for (int i = tid; i < N_CAND / 8; i += 1024) {
        const uint4 v = ((const uint4*)krow)[i];
        const unsigned w[4] = {v.x, v.y, v.z, v.w};
        #pragma unroll
        for (int e = 0; e < 4; ++e) {
            const unsigned k0 = w[e] & 0xFFFFu, k1 = w[e] >> 16;
            const int n0 = i * 8 + e * 2, n1 = n0 + 1;
            if (k0 < T16) {
                const int p = atomicAdd(&cntLess, 1);
                idx_out[row * CTX + p] = n0;
            } else if (k0 == T16) {
                const int p = atomicAdd(&cntEq, 1);
                if (p < MAXTIE) tiebuf[(size_t)row * MAXTIE + p] = n0;
            }
            if (k1 < T16) {
                const int p = atomicAdd(&cntLess, 1);
                idx_out[row * CTX + p] = n1;
            } else if (k1 == T16) {
                const int p = atomicAdd(&cntEq, 1);
                if (p < MAXTIE) tiebuf[(size_t)row * MAXTIE + p] = n1;
            }
        }
    }
    __syncthreads();
    if (tid == 0) {
        lesscnt[row] = cntLess;
        tiecnt[row] = (cntEq < MAXTIE) ? cntEq : MAXTIE;
    }
}

// ---------------------------------------------------------------------------
// Exact fp32 tie-break: fill idx_out[less..96) with the (96-less) smallest
// exact partial distances among the tied candidates.
// ---------------------------------------------------------------------------
__global__ __launch_bounds__(256)
void tiebreak_kernel(const float* __restrict__ k_x, const float* __restrict__ cand_k,
                     const float* __restrict__ ck2, const int* __restrict__ tiebuf,
                     const int* __restrict__ tiecnt, const int* __restrict__ lesscnt,
                     int* __restrict__ idx_out)
{
    const int row = blockIdx.x;
    const int tid = threadIdx.x;
    const int T = tiecnt[row];
    const int less = lesscnt[row];
    const int need = CTX - less;
    if (need <= 0) return;

    if (T <= need) {   // all ties selected
        for (int t = tid; t < T; t += 256)
            idx_out[row * CTX + less + t] = tiebuf[(size_t)row * MAXTIE + t];
        return;
    }

    __shared__ float sv[MAXTIE];
    const float* kv = k_x + (size_t)row * D_MAIN;
    for (int t = tid; t < T; t += 256) {
        const int c = tiebuf[(size_t)row * MAXTIE + t];
        const float* cv = cand_k + (size_t)c * D_MAIN;
        float s = 0.f;
        for (int d = 0; d < D_MAIN; d += 4) {
            const float4 a = *(const float4*)(kv + d);
            const float4 q = *(const float4*)(cv + d);
            s += a.x*q.x + a.y*q.y + a.z*q.z + a.w*q.w;
        }
        sv[t] = ck2[c] - 2.f * s;
    }
    __syncthreads();

    // radix select `need` smallest among sv[0..T)
    __shared__ unsigned hist[256];
    __shared__ unsigned sh_bin, sh_need;
    unsigned prefix = 0;
    int plen = 0;
    int nd = need;
    for (int pass = 0; pass < 4; ++pass) {
        const int shift = 24 - 8 * pass;
        hist[tid] = 0;
        __syncthreads();
        for (int t = tid; t < T; t += 256) {
            const unsigned u = f2u_mono(sv[t]);
            if (plen == 0 || (u >> (32 - plen)) == prefix)
                atomicAdd(&hist[(u >> shift) & 255u], 1u);
        }
        __syncthreads();
        if (tid == 0) {
            int cum = 0;
            for (int bb = 0; bb < 256; ++bb) {
                const int h = (int)hist[bb];
                if (cum + h >= nd) { sh_bin = (unsigned)bb; sh_need = (unsigned)(nd - cum); break; }
                cum += h;
            }
        }
        __syncthreads();
        prefix = (prefix << 8) | sh_bin;
        nd = (int)sh_need;
        plen += 8;
        __syncthreads();
    }
    const unsigned Tf = prefix;
    const int nl2 = need - nd;
    __shared__ int c1, c2;
    if (tid == 0) { c1 = 0; c2 = 0; }
    __syncthreads();
    for (int t = tid; t < T; t += 256) {
        const unsigned u = f2u_mono(sv[t]);
        if (u < Tf) {
            const int p = atomicAdd(&c1, 1);
            idx_out[row * CTX + less + p] = tiebuf[(size_t)row * MAXTIE + t];
        } else if (u == Tf) {
            const int p = atomicAdd(&c2, 1);
            if (p < nd) idx_out[row * CTX + less + nl2 + p] = tiebuf[(size_t)row * MAXTIE + t];
        }
    }
}

// ---------------------------------------------------------------------------
// Exact fp32 partial distance for the selected 96 (one wave per (b,c))
// ---------------------------------------------------------------------------
__global__ __launch_bounds__(256)
void sim_exact_kernel(const float* __restrict__ k_x, const float* __restrict__ cand_k,
                      const float* __restrict__ ck2, const int* __restrict__ idx,
                      float* __restrict__ sval)
{
    const int bc = blockIdx.x * 4 + (threadIdx.x >> 6);
    const int lane = threadIdx.x & 63;
    const int b = bc / CTX;
    const int id = idx[bc];
    const float4 kv = *(const float4*)(k_x + (size_t)b * D_MAIN + lane * 4);
    const float4 cv = *(const float4*)(cand_k + (size_t)id * D_MAIN + lane * 4);
    float s = kv.x*cv.x + kv.y*cv.y + kv.z*cv.z + kv.w*cv.w;
    #pragma unroll
    for (int off = 32; off; off >>= 1) s += __shfl_down(s, off, 64);
    if (lane == 0) sval[bc] = ck2[id] - 2.f * s;
}

// ---------------------------------------------------------------------------
// softmax over 96 slots
// ---------------------------------------------------------------------------
__global__ __launch_bounds__(128)
void softmax96_kernel(const float* __restrict__ sval, float* __restrict__ probs)
{
    __shared__ float sh[128];
    const int row = blockIdx.x, tid = threadIdx.x;
    const float v = (tid < CTX) ? -sval[row * CTX + tid] : -1e30f;
    sh[tid] = v;
    __syncthreads();
    for (int s = 64; s > 0; s >>= 1) {
        if (tid < s) sh[tid] = fmaxf(sh[tid], sh[tid + s]);
        __syncthreads();
    }
    const float m = sh[0];
    __syncthreads();
    const float e = (tid < CTX) ? __expf(v - m) : 0.f;
    sh[tid] = e;
    __syncthreads();
    for (int s = 64; s > 0; s >>= 1) {
        if (tid < s) sh[tid] += sh[tid + s];
        __syncthreads();
    }
    if (tid < CTX) probs[row * CTX + tid] = e / sh[0];
}

// ---------------------------------------------------------------------------
// diff split
// ---------------------------------------------------------------------------
__global__ __launch_bounds__(256)
void build_diff_kernel(const float* __restrict__ k_x, const float* __restrict__ cand_k,
                       const int* __restrict__ idx, u16* __restrict__ dh,
                       u16* __restrict__ dl)
{
    const int bc = blockIdx.x;
    const int b = bc / CTX;
    const int d = threadIdx.x;
    const int id = idx[bc];
    const float v = k_x[(size_t)b * D_MAIN + d] - cand_k[(size_t)id * D_MAIN + d];
    u16 h, l; split_f32(v, h, l);
    dh[(size_t)bc * D_MAIN + d] = h;
    dl[(size_t)bc * D_MAIN + d] = l;
}

// ---------------------------------------------------------------------------
// h[b,d] += sum_c probs[b,c] * (label_emb[cand_y[idx[b,c]], d] + v[(b,c), d])
// ---------------------------------------------------------------------------
__global__ __launch_bounds__(256)
void mix_reduce_kernel(float* __restrict__ h, const float* __restrict__ v,
                       const float* __restrict__ probs, const int* __restrict__ idx,
                       const int* __restrict__ cy, const float* __restrict__ label_emb)
{
    const int b = blockIdx.x;
    const int d = threadIdx.x;
    float acc = 0.f;
    for (int c = 0; c < CTX; ++c) {
        const int bc = b * CTX + c;
        const int id = idx[bc];
        const int y = cy[id];
        const float val = label_emb[(size_t)y * D_MAIN + d] + v[(size_t)bc * D_MAIN + d];
        acc = fmaf(probs[bc], val, acc);
    }
    h[(size_t)b * D_MAIN + d] += acc;
}

// ---------------------------------------------------------------------------
// host-side orchestration
// ---------------------------------------------------------------------------
static inline dim3 g128(int M, int N) {
    return dim3((unsigned)((N + 127) / 128), (unsigned)((M + 127) / 128));
}

struct EncW {
    const u16 *WlinTh, *WlinTl, *e0W1Th, *e0W1Tl, *e0W2Th, *e0W2Tl,
              *e1W1Th, *e1W1Tl, *e1W2Th, *e1W2Tl, *KWTh, *KWTl;
    const float *b_lin, *e0b1, *e0b2, *e1g, *e1b, *e1b1, *e1b2, *mixg, *mixb, *Kb;
};

static void encode_rows_split(const u16* Xh, const u16* Xl, int R, const EncW& w,
                              float* H, u16* Hh, u16* Hl, u16* Th, u16* Tl,
                              u16* TNh, u16* TNl, float* Kf, u16* Kh, u16* Kl,
                              hipStream_t stream)
{
    dim3 blk(256);
    gemm_split_nt<false,true,false,false,true,true,false,true><<<g128(R, D_MAIN), blk, 0, stream>>>(
        Xh, Xl, w.WlinTh, w.WlinTl, w.b_lin, nullptr, H, Hh, Hl, R, D_MAIN, D_IN);
    gemm_split_nt<true,true,false,false,false,true,false,true><<<g128(R, D_BLOCK), blk, 0, stream>>>(
        Hh, Hl, w.e0W1Th, w.e0W1Tl, w.e0b1, nullptr, nullptr, Th, Tl, R, D_BLOCK, D_MAIN);
    gemm_split_nt<false,true,true,false,true,false,false,true><<<g128(R, D_MAIN), blk, 0, stream>>>(
        Th, Tl, w.e0W2Th, w.e0W2Tl, w.e0b2, H, H, nullptr, nullptr, R, D_MAIN, D_BLOCK);
    ln_kernel<false,true><<<R, 256, 0, stream>>>(H, w.e1g, w.e1b, nullptr, TNh, TNl);
    gemm_split_nt<true,true,false,false,false,true,false,true><<<g128(R, D_BLOCK), blk, 0, stream>>>(
        TNh, TNl, w.e1W1Th, w.e1W1Tl, w.e1b1, nullptr, nullptr, Th, Tl, R, D_BLOCK, D_MAIN);
    gemm_split_nt<false,true,true,false,true,false,false,true><<<g128(R, D_MAIN), blk, 0, stream>>>(
        Th, Tl, w.e1W2Th, w.e1W2Tl, w.e1b2, H, H, nullptr, nullptr, R, D_MAIN, D_BLOCK);
    ln_kernel<false,true><<<R, 256, 0, stream>>>(H, w.mixg, w.mixb, nullptr, TNh, TNl);
    gemm_split_nt<false,true,false,false,true,true,false,true><<<g128(R, D_MAIN), blk, 0, stream>>>(
        TNh, TNl, w.KWTh, w.KWTl, w.Kb, nullptr, Kf, Kh, Kl, R, D_MAIN, D_MAIN);
}

extern "C" void kernel_launch(void* const* d_in, const int* in_sizes, int n_in,
                              void* d_out, int out_size, void* d_ws, size_t ws_size,
                              hipStream_t stream)
{
    const float* x        = (const float*)d_in[0];
    const float* cand_x   = (const float*)d_in[1];
    const int*   cand_y   = (const int*)  d_in[2];
    const float* W_lin    = (const float*)d_in[4];
    const float* b_lin    = (const float*)d_in[5];
    const float* e0W1     = (const float*)d_in[6];
    const float* e0b1     = (const float*)d_in[7];
    const float* e0W2     = (const float*)d_in[8];
    const float* e0b2     = (const float*)d_in[9];
    const float* e1g      = (const float*)d_in[10];
    const float* e1b      = (const float*)d_in[11];
    const float* e1W1     = (const float*)d_in[12];
    const float* e1b1     = (const float*)d_in[13];
    const float* e1W2     = (const float*)d_in[14];
    const float* e1b2     = (const float*)d_in[15];
    const float* mixg     = (const float*)d_in[16];
    const float* mixb     = (const float*)d_in[17];
    const float* K_W      = (const float*)d_in[18];
    const float* K_b      = (const float*)d_in[19];
    const float* label_emb= (const float*)d_in[20];
    const float* T_W1     = (const float*)d_in[21];
    const float* T_b1     = (const float*)d_in[22];
    const float* T_W2     = (const float*)d_in[23];
    const float* p0g      = (const float*)d_in[24];
    const float* p0b      = (const float*)d_in[25];
    const float* p0W1     = (const float*)d_in[26];
    const float* p0b1     = (const float*)d_in[27];
    const float* p0W2     = (const float*)d_in[28];
    const float* p0b2     = (const float*)d_in[29];
    const float* p1g      = (const float*)d_in[30];
    const float* p1b      = (const float*)d_in[31];
    const float* p1W1     = (const float*)d_in[32];
    const float* p1b1     = (const float*)d_in[33];
    const float* p1W2     = (const float*)d_in[34];
    const float* p1b2     = (const float*)d_in[35];
    const float* headg    = (const float*)d_in[36];
    const float* headb    = (const float*)d_in[37];
    const float* head_W   = (const float*)d_in[38];
    const float* head_bias= (const float*)d_in[39];

    char* ws = (char*)d_ws;
    size_t off = 0;
    auto alloc = [&](size_t bytes) -> char* {
        char* p = ws + off;
        off += (bytes + 255) & ~(size_t)255;
        return p;
    };

    // persistent (~163 MB)
    float* cand_k  = (float*)alloc((size_t)N_CAND * D_MAIN * 4);
    u16* cand_k_h  = (u16*)alloc((size_t)N_CAND * D_MAIN * 2);
    u16* cand_k_l  = (u16*)alloc((size_t)N_CAND * D_MAIN * 2);
    u16* cand_x_h  = (u16*)alloc((size_t)N_CAND * D_IN * 2);
    u16* cand_x_l  = (u16*)alloc((size_t)N_CAND * D_IN * 2);
    u16* x_h       = (u16*)alloc((size_t)B_ROWS * D_IN * 2);
    u16* x_l       = (u16*)alloc((size_t)B_ROWS * D_IN * 2);
    float* ck2     = (float*)alloc((size_t)N_CAND * 4);
    float* h_x     = (float*)alloc((size_t)B_ROWS * D_MAIN * 4);
    float* tn_x    = (float*)alloc((size_t)B_ROWS * D_MAIN * 4);
    float* t_x     = (float*)alloc((size_t)B_ROWS * D_BLOCK * 4);
    float* k_x     = (float*)alloc((size_t)B_ROWS * D_MAIN * 4);
    u16* xe_Hh     = (u16*)alloc((size_t)B_ROWS * D_MAIN * 2);
    u16* xe_Hl     = (u16*)alloc((size_t)B_ROWS * D_MAIN * 2);
    u16* xe_Th     = (u16*)alloc((size_t)B_ROWS * D_BLOCK * 2);
    u16* xe_Tl     = (u16*)alloc((size_t)B_ROWS * D_BLOCK * 2);
    u16* xe_TNh    = (u16*)alloc((size_t)B_ROWS * D_MAIN * 2);
    u16* xe_TNl    = (u16*)alloc((size_t)B_ROWS * D_MAIN * 2);
    u16* k_x_h     = (u16*)alloc((size_t)B_ROWS * D_MAIN * 2);
    u16* k_x_l     = (u16*)alloc((size_t)B_ROWS * D_MAIN * 2);
    int*   idx     = (int*)  alloc((size_t)B_ROWS * CTX * 4);
    float* sval    = (float*)alloc((size_t)B_ROWS * CTX * 4);
    float* probs   = (float*)alloc((size_t)B_ROWS * CTX * 4);
    int* tiebuf    = (int*)  alloc((size_t)B_ROWS * MAXTIE * 4);   // 16.8 MB
    int* tiecnt    = (int*)  alloc((size_t)B_ROWS * 4);
    int* lesscnt   = (int*)  alloc((size_t)B_ROWS * 4);

    // transposed split weights (~3.6 MB)
    u16* WlinTh = (u16*)alloc((size_t)D_IN  * D_MAIN * 2);
    u16* WlinTl = (u16*)alloc((size_t)D_IN  * D_MAIN * 2);
    u16* e0W1Th = (u16*)alloc((size_t)D_MAIN* D_BLOCK * 2);
    u16* e0W1Tl = (u16*)alloc((size_t)D_MAIN* D_BLOCK * 2);
    u16* e0W2Th = (u16*)alloc((size_t)D_BLOCK*D_MAIN * 2);
    u16* e0W2Tl = (u16*)alloc((size_t)D_BLOCK*D_MAIN * 2);
    u16* e1W1Th = (u16*)alloc((size_t)D_MAIN* D_BLOCK * 2);
    u16* e1W1Tl = (u16*)alloc((size_t)D_MAIN* D_BLOCK * 2);
    u16* e1W2Th = (u16*)alloc((size_t)D_BLOCK*D_MAIN * 2);
    u16* e1W2Tl = (u16*)alloc((size_t)D_BLOCK*D_MAIN * 2);
    u16* KWTh   = (u16*)alloc((size_t)D_MAIN* D_MAIN * 2);
    u16* KWTl   = (u16*)alloc((size_t)D_MAIN* D_MAIN * 2);
    u16* TW1Th  = (u16*)alloc((size_t)D_MAIN* D_BLOCK * 2);
    u16* TW1Tl  = (u16*)alloc((size_t)D_MAIN* D_BLOCK * 2);
    u16* TW2Th  = (u16*)alloc((size_t)D_BLOCK*D_MAIN * 2);
    u16* TW2Tl  = (u16*)alloc((size_t)D_BLOCK*D_MAIN * 2);

    const size_t pool_avail = (ws_size > off) ? (ws_size - off) : 0;
    int rc_enc = (int)(pool_avail / 5120);
    if (rc_enc > 25000) rc_enc = 25000;
    if (rc_enc < 6250)  rc_enc = 6250;
    int mb_ch = (int)(pool_avail / ((size_t)2 * N_CAND));   // u16 keys now
    if (mb_ch > B_ROWS) mb_ch = B_ROWS;
    if (mb_ch < 128)    mb_ch = 128;
    // T-MLP chunk: per b-row = 96*(1024 diff-split + 1024 t2-hi + 1024 v-f32) B
    int bb_ch = (int)(pool_avail / ((size_t)CTX * 3072));
    if (bb_ch > B_ROWS) bb_ch = B_ROWS;
    if (bb_ch < 64)     bb_ch = 64;

    char* pool = ws + off;
    dim3 blk(256);

    // 0) input + weight conversions
    {
        f32_to_split_kernel<<<(B_ROWS*D_IN + 255)/256, blk, 0, stream>>>(x, x_h, x_l, B_ROWS*D_IN);
        f32_to_split_kernel<<<(N_CAND*D_IN + 255)/256, blk, 0, stream>>>(cand_x, cand_x_h, cand_x_l, N_CAND*D_IN);
        auto tr = [&](const float* s, u16* dh, u16* dl, int R, int C) {
            transpose_split_kernel<<<(R*C + 255)/256, blk, 0, stream>>>(s, dh, dl, R, C);
        };
        tr(W_lin, WlinTh, WlinTl, D_IN,   D_MAIN);
        tr(e0W1,  e0W1Th, e0W1Tl, D_MAIN, D_BLOCK);
        tr(e0W2,  e0W2Th, e0W2Tl, D_BLOCK,D_MAIN);
        tr(e1W1,  e1W1Th, e1W1Tl, D_MAIN, D_BLOCK);
        tr(e1W2,  e1W2Th, e1W2Tl, D_BLOCK,D_MAIN);
        tr(K_W,   KWTh,   KWTl,   D_MAIN, D_MAIN);
        tr(T_W1,  TW1Th,  TW1Tl,  D_MAIN, D_BLOCK);
        tr(T_W2,  TW2Th,  TW2Tl,  D_BLOCK,D_MAIN);
    }

    EncW w = { WlinTh, WlinTl, e0W1Th, e0W1Tl, e0W2Th, e0W2Tl,
               e1W1Th, e1W1Tl, e1W2Th, e1W2Tl, KWTh, KWTl,
               b_lin, e0b1, e0b2, e1g, e1b, e1b1, e1b2, mixg, mixb, K_b };

    // 1) encode candidates
    for (int r0 = 0; r0 < N_CAND; r0 += rc_enc) {
        const int R = (N_CAND - r0 < rc_enc) ? (N_CAND - r0) : rc_enc;
        char* p = pool;
        float* Hc = (float*)p;        p += (size_t)rc_enc * D_MAIN * 4;
        u16* Hh  = (u16*)p;           p += (size_t)rc_enc * D_MAIN * 2;
        u16* Hl  = (u16*)p;           p += (size_t)rc_enc * D_MAIN * 2;
        u16* Th  = (u16*)p;           p += (size_t)rc_enc * D_BLOCK * 2;
        u16* Tl  = (u16*)p;           p += (size_t)rc_enc * D_BLOCK * 2;
        u16* TNh = (u16*)p;           p += (size_t)rc_enc * D_MAIN * 2;
        u16* TNl = (u16*)p;
        encode_rows_split(cand_x_h + (size_t)r0 * D_IN, cand_x_l + (size_t)r0 * D_IN,
                          R, w, Hc, Hh, Hl, Th, Tl, TNh, TNl,
                          cand_k + (size_t)r0 * D_MAIN,
                          cand_k_h + (size_t)r0 * D_MAIN,
                          cand_k_l + (size_t)r0 * D_MAIN, stream);
    }

    // 2) encode x
    encode_rows_split(x_h, x_l, B_ROWS, w, h_x, xe_Hh, xe_Hl, xe_Th, xe_Tl,
                      xe_TNh, xe_TNl, k_x, k_x_h, k_x_l, stream);

    // 3) candidate norms
    cn2_kernel<<<N_CAND, 64, 0, stream>>>(cand_k, ck2);

    // 4+5) distance keys (u16) + top-96 select
    for (int m0 = 0; m0 < B_ROWS; m0 += mb_ch) {
        const int R = (B_ROWS - m0 < mb_ch) ? (B_ROWS - m0) : mb_ch;
        u16* s_keys = (u16*)pool;
        gemm_split_nt<false,false,false,true,false,false,false,true><<<g128(R, N_CAND), blk, 0, stream>>>(
            k_x_h + (size_t)m0 * D_MAIN, k_x_l + (size_t)m0 * D_MAIN,
            cand_k_h, cand_k_l, ck2, nullptr, nullptr, s_keys, nullptr,
            R, N_CAND, D_MAIN);
        topk96_u16_kernel<<<R, 1024, 0, stream>>>(
            s_keys, idx + m0 * CTX, tiebuf + (size_t)m0 * MAXTIE,
            tiecnt + m0, lesscnt + m0);
    }

    // 5b) exact fp32 tie-break fills idx[less..96)
    tiebreak_kernel<<<B_ROWS, 256, 0, stream>>>(k_x, cand_k, ck2, tiebuf, tiecnt,
                                                lesscnt, idx);

    // 5c) exact fp32 sval for selected 96
    sim_exact_kernel<<<B_ROWS * CTX / 4, 256, 0, stream>>>(k_x, cand_k, ck2, idx, sval);

    // 6) softmax
    softmax96_kernel<<<B_ROWS, 128, 0, stream>>>(sval, probs);

    // 7-10) T-MLP (GEMM1 -> bf16 t2 only; GEMM2 A-lo dropped) + mix
    for (int b0 = 0; b0 < B_ROWS; b0 += bb_ch) {
        const int rows = (B_ROWS - b0 < bb_ch) ? (B_ROWS - b0) : bb_ch;
        const int R = rows * CTX;
        char* p = pool;
        u16* dh = (u16*)p;  p += (size_t)bb_ch * CTX * D_MAIN * 2;
        u16* dl = (u16*)p;  p += (size_t)bb_ch * CTX * D_MAIN * 2;
        u16* th = (u16*)p;  p += (size_t)bb_ch * CTX * D_BLOCK * 2;
        float* v = (float*)p;
        build_diff_kernel<<<R, 256, 0, stream>>>(
            k_x + (size_t)b0 * D_MAIN, cand_k, idx + b0 * CTX, dh, dl);
        gemm_split_nt<true,true,false,false,false,false,true,true><<<g128(R, D_BLOCK), blk, 0, stream>>>(
            dh, dl, TW1Th, TW1Tl, T_b1, nullptr, nullptr, th, nullptr, R, D_BLOCK, D_MAIN);
        gemm_split_nt<false,false,false,false,true,false,false,false><<<g128(R, D_MAIN), blk, 0, stream>>>(
            th, nullptr, TW2Th, TW2Tl, nullptr, nullptr, v, nullptr, nullptr, R, D_MAIN, D_BLOCK);
        mix_reduce_kernel<<<rows, 256, 0, stream>>>(
            h_x + (size_t)b0 * D_MAIN, v, probs + b0 * CTX, idx + b0 * CTX,
            cand_y, label_emb);
    }

    // 11) post blocks (fp32)
    ln_kernel<false,false><<<B_ROWS, 256, 0, stream>>>(h_x, p0g, p0b, tn_x, nullptr, nullptr);
    gemm128<true, true,false><<<g128(B_ROWS, D_BLOCK), blk, 0, stream>>>(tn_x, p0W1, p0b1, nullptr, t_x, B_ROWS, D_BLOCK, D_MAIN);
    gemm128<false,true,true ><<<g128(B_ROWS, D_MAIN), blk, 0, stream>>>(t_x, p0W2, p0b2, h_x, h_x, B_ROWS, D_MAIN, D_BLOCK);
    ln_kernel<false,false><<<B_ROWS, 256, 0, stream>>>(h_x, p1g, p1b, tn_x, nullptr, nullptr);
    gemm128<true, true,false><<<g128(B_ROWS, D_BLOCK), blk, 0, stream>>>(tn_x, p1W1, p1b1, nullptr, t_x, B_ROWS, D_BLOCK, D_MAIN);
    gemm128<false,true,true ><<<g128(B_ROWS, D_MAIN), blk, 0, stream>>>(t_x, p1W2, p1b2, h_x, h_x, B_ROWS, D_MAIN, D_BLOCK);

    // 12) head (fp32)
    ln_kernel<true,false><<<B_ROWS, 256, 0, stream>>>(h_x, headg, headb, tn_x, nullptr, nullptr);
    gemm_head<<<dim3(1, (B_ROWS + 63) / 64), blk, 0, stream>>>(
        tn_x, head_W, head_bias, (float*)d_out, B_ROWS, N_OUT, D_MAIN);
}

// Round 8
// 1842.233 us; speedup vs baseline: 3.4687x; 1.1678x over previous
//
#include <hip/hip_runtime.h>
#include <hip/hip_bf16.h>
#include <cstdint>
#include <cstddef>

#define B_ROWS 1024
#define N_CAND 50000
#define CTX    96
#define D_IN   128
#define D_MAIN 256
#define D_BLOCK 512
#define N_OUT  10
#define LN_EPS 1e-5f
#define MAXTIE 4096

typedef unsigned short u16;
typedef __attribute__((ext_vector_type(8))) short bf16x8;
typedef __attribute__((ext_vector_type(4))) float f32x4;

__device__ __forceinline__ u16 bf16_bits(float f) {
    __hip_bfloat16 h = __float2bfloat16(f);
    return *reinterpret_cast<u16*>(&h);
}
__device__ __forceinline__ float bits_to_f32(u16 b) {
    unsigned u = ((unsigned)b) << 16;
    return __uint_as_float(u);
}
__device__ __forceinline__ void split_f32(float v, u16& h, u16& l) {
    h = bf16_bits(v);
    l = bf16_bits(v - bits_to_f32(h));
}
__device__ __forceinline__ float join_f32(u16 h, u16 l) {
    return bits_to_f32(h) + bits_to_f32(l);
}
__device__ __forceinline__ unsigned f2u_mono(float f) {
    unsigned u = __float_as_uint(f);
    return u ^ ((u & 0x80000000u) ? 0xFFFFFFFFu : 0x80000000u);
}

// async global->LDS 16B per lane (dest = wave-uniform base + lane*16)
__device__ __forceinline__ void load_lds_16B(const void* gp, void* lp) {
    __builtin_amdgcn_global_load_lds((const __attribute__((address_space(1))) void*)gp,
                                     (__attribute__((address_space(3))) void*)lp,
                                     16, 0, 0);
}

// ---------------------------------------------------------------------------
// Split-bf16 MFMA GEMM (NT): C = epilogue( A[MxK] @ B[NxK]^T ), ~fp32 quality.
// A = Ah(+Al if A_LO), B = Bh+Bl. acc += AhBh (+AlBh) + AhBl.
// 128x128 tile, BK=32, 256 threads, 16x16x32 MFMA.
// KEY16: C -> u16 monotone key of (-2*acc + bias[n]) into Ch.
// ---------------------------------------------------------------------------
template<bool RELU, bool HAS_BIAS, bool HAS_RES, bool KEY16,
         bool OUT_F32, bool OUT_SPLIT, bool OUT_B16, bool A_LO>
__global__ __launch_bounds__(256)
void gemm_split_nt(const u16* __restrict__ Ah, const u16* __restrict__ Al,
                   const u16* __restrict__ Bh, const u16* __restrict__ Bl,
                   const float* __restrict__ bias, const float* __restrict__ Rm,
                   float* __restrict__ Cf, u16* __restrict__ Ch, u16* __restrict__ Cl,
                   int M, int N, int K)
{
    __shared__ __align__(16) u16 Ash[128 * 32];
    __shared__ __align__(16) u16 Asl[A_LO ? 128 * 32 : 8];
    __shared__ __align__(16) u16 Bsh[128 * 32];
    __shared__ __align__(16) u16 Bsl[128 * 32];

    const int tid  = threadIdx.x;
    const int wave = tid >> 6, lane = tid & 63;
    const int bm = blockIdx.y * 128, bn = blockIdx.x * 128;
    const int wm = (wave >> 1) * 64, wn = (wave & 1) * 64;
    const int l16 = lane & 15, quad = lane >> 4;

    const int srow = lane >> 2;          // 0..15
    const int scol = (lane & 3) * 8;     // 0,8,16,24 (u16 elems)

    f32x4 acc[4][4];
    #pragma unroll
    for (int i = 0; i < 4; ++i)
        #pragma unroll
        for (int j = 0; j < 4; ++j)
            acc[i][j] = (f32x4){0.f, 0.f, 0.f, 0.f};

    for (int k0 = 0; k0 < K; k0 += 32) {
        const int r0 = wave * 16 + srow, r1 = r0 + 64;
        int ga0 = bm + r0; if (ga0 > M - 1) ga0 = M - 1;
        int ga1 = bm + r1; if (ga1 > M - 1) ga1 = M - 1;
        int gb0 = bn + r0; if (gb0 > N - 1) gb0 = N - 1;
        int gb1 = bn + r1; if (gb1 > N - 1) gb1 = N - 1;
        const size_t a0 = (size_t)ga0 * K + k0 + scol;
        const size_t a1 = (size_t)ga1 * K + k0 + scol;
        const size_t b0 = (size_t)gb0 * K + k0 + scol;
        const size_t b1 = (size_t)gb1 * K + k0 + scol;

        load_lds_16B(Ah + a0, &Ash[(wave * 16) * 32]);
        load_lds_16B(Ah + a1, &Ash[(64 + wave * 16) * 32]);
        if (A_LO) {
            load_lds_16B(Al + a0, &Asl[(wave * 16) * 32]);
            load_lds_16B(Al + a1, &Asl[(64 + wave * 16) * 32]);
        }
        load_lds_16B(Bh + b0, &Bsh[(wave * 16) * 32]);
        load_lds_16B(Bh + b1, &Bsh[(64 + wave * 16) * 32]);
        load_lds_16B(Bl + b0, &Bsl[(wave * 16) * 32]);
        load_lds_16B(Bl + b1, &Bsl[(64 + wave * 16) * 32]);
        __syncthreads();

        bf16x8 ah[4], al[4], bh[4], bl[4];
        #pragma unroll
        for (int i = 0; i < 4; ++i) {
            ah[i] = *(const bf16x8*)&Ash[(wm + i * 16 + l16) * 32 + quad * 8];
            if (A_LO) al[i] = *(const bf16x8*)&Asl[(wm + i * 16 + l16) * 32 + quad * 8];
        }
        #pragma unroll
        for (int j = 0; j < 4; ++j) {
            bh[j] = *(const bf16x8*)&Bsh[(wn + j * 16 + l16) * 32 + quad * 8];
            bl[j] = *(const bf16x8*)&Bsl[(wn + j * 16 + l16) * 32 + quad * 8];
        }

        #pragma unroll
        for (int i = 0; i < 4; ++i)
            #pragma unroll
            for (int j = 0; j < 4; ++j) {
                acc[i][j] = __builtin_amdgcn_mfma_f32_16x16x32_bf16(ah[i], bh[j], acc[i][j], 0, 0, 0);
                if (A_LO)
                    acc[i][j] = __builtin_amdgcn_mfma_f32_16x16x32_bf16(al[i], bh[j], acc[i][j], 0, 0, 0);
                acc[i][j] = __builtin_amdgcn_mfma_f32_16x16x32_bf16(ah[i], bl[j], acc[i][j], 0, 0, 0);
            }
        __syncthreads();
    }

    // epilogue: C/D layout col=lane&15 (N), row=quad*4+reg (M)
    #pragma unroll
    for (int j = 0; j < 4; ++j) {
        const int n = bn + wn + j * 16 + l16;
        if (n >= N) continue;
        float bv = 0.f;
        if (HAS_BIAS || KEY16) bv = bias[n];
        #pragma unroll
        for (int i = 0; i < 4; ++i) {
            #pragma unroll
            for (int r = 0; r < 4; ++r) {
                const int m = bm + wm + i * 16 + quad * 4 + r;
                if (m >= M) continue;
                float v = acc[i][j][r];
                if (KEY16) {
                    v = -2.f * v + bv;
                    Ch[(size_t)m * N + n] = (u16)(f2u_mono(v) >> 16);
                } else {
                    if (HAS_BIAS) v += bv;
                    if (RELU)     v = fmaxf(v, 0.f);
                    if (HAS_RES)  v += Rm[(size_t)m * N + n];
                    if (OUT_F32)  Cf[(size_t)m * N + n] = v;
                    if (OUT_SPLIT) {
                        u16 h, l; split_f32(v, h, l);
                        Ch[(size_t)m * N + n] = h;
                        Cl[(size_t)m * N + n] = l;
                    }
                    if (OUT_B16) Ch[(size_t)m * N + n] = bf16_bits(v);
                }
            }
        }
    }
}

// ---------------------------------------------------------------------------
// fp32 128x128 GEMM (post blocks): 8x8 micro-tile. B row-major [KxN].
// ---------------------------------------------------------------------------
template<bool RELU, bool HAS_BIAS, bool HAS_RES>
__global__ __launch_bounds__(256)
void gemm128(const float* __restrict__ A, const float* __restrict__ Bm,
             const float* __restrict__ bias, const float* __restrict__ Rm,
             float* __restrict__ C, int M, int N, int K)
{
    __shared__ float As[16][128];
    __shared__ float Bs[16][128];
    const int tid = threadIdx.x;
    const int bm = blockIdx.y * 128;
    const int bn = blockIdx.x * 128;

    const int ar = tid >> 1;
    const int ak = (tid & 1) << 3;
    const int kb = tid >> 4;
    const int nb0 = (tid & 15) << 3;
    const int my = (tid >> 4) << 3;
    const int nx = (tid & 15) << 3;

    float acc[8][8] = {};

    for (int k0 = 0; k0 < K; k0 += 16) {
        {
            float4 v0 = make_float4(0.f,0.f,0.f,0.f), v1 = v0;
            const int gm = bm + ar;
            if (gm < M) {
                const float* ap = A + (size_t)gm * K + k0 + ak;
                v0 = *(const float4*)ap;
                v1 = *(const float4*)(ap + 4);
            }
            As[ak+0][ar]=v0.x; As[ak+1][ar]=v0.y; As[ak+2][ar]=v0.z; As[ak+3][ar]=v0.w;
            As[ak+4][ar]=v1.x; As[ak+5][ar]=v1.y; As[ak+6][ar]=v1.z; As[ak+7][ar]=v1.w;
        }
        {
            const float* bp = Bm + (size_t)(k0 + kb) * N + bn + nb0;
            *(float4*)&Bs[kb][nb0]   = *(const float4*)bp;
            *(float4*)&Bs[kb][nb0+4] = *(const float4*)(bp + 4);
        }
        __syncthreads();

        #pragma unroll
        for (int k = 0; k < 16; ++k) {
            float a[8], b[8];
            *(float4*)&a[0] = *(const float4*)&As[k][my];
            *(float4*)&a[4] = *(const float4*)&As[k][my+4];
            *(float4*)&b[0] = *(const float4*)&Bs[k][nx];
            *(float4*)&b[4] = *(const float4*)&Bs[k][nx+4];
            #pragma unroll
            for (int i = 0; i < 8; ++i)
                #pragma unroll
                for (int j = 0; j < 8; ++j)
                    acc[i][j] = fmaf(a[i], b[j], acc[i][j]);
        }
        __syncthreads();
    }

    #pragma unroll
    for (int i = 0; i < 8; ++i) {
        const int m = bm + my + i;
        if (m >= M) continue;
        #pragma unroll
        for (int j = 0; j < 8; j += 4) {
            const int n = bn + nx + j;
            if (n >= N) continue;
            float4 v = make_float4(acc[i][j], acc[i][j+1], acc[i][j+2], acc[i][j+3]);
            if (HAS_BIAS) {
                const float4 q = *(const float4*)(bias + n);
                v.x += q.x; v.y += q.y; v.z += q.z; v.w += q.w;
            }
            if (RELU) {
                v.x = fmaxf(v.x, 0.f); v.y = fmaxf(v.y, 0.f);
                v.z = fmaxf(v.z, 0.f); v.w = fmaxf(v.w, 0.f);
            }
            if (HAS_RES) {
                const float4 q = *(const float4*)(Rm + (size_t)m * N + n);
                v.x += q.x; v.y += q.y; v.z += q.z; v.w += q.w;
            }
            *(float4*)(C + (size_t)m * N + n) = v;
        }
    }
}

// ---------------------------------------------------------------------------
// Small-N fp32 GEMM (head, N=10)
// ---------------------------------------------------------------------------
__global__ __launch_bounds__(256)
void gemm_head(const float* __restrict__ A, const float* __restrict__ Bm,
               const float* __restrict__ bias, float* __restrict__ C,
               int M, int N, int K)
{
    __shared__ float As[16][64];
    __shared__ float Bs[16][64];
    const int tid = threadIdx.x;
    const int bm = blockIdx.y * 64;

    const int a_m = tid >> 2;
    const int a_k = (tid & 3) << 2;
    const int b_k = tid >> 4;
    const int b_n = (tid & 15) << 2;
    const int my = (tid >> 4) << 2;
    const int nx = (tid & 15) << 2;

    float acc[4][4] = {};

    for (int k0 = 0; k0 < K; k0 += 16) {
        float4 av = make_float4(0.f,0.f,0.f,0.f);
        const int gm = bm + a_m;
        if (gm < M) av = *(const float4*)(A + (size_t)gm * K + k0 + a_k);
        As[a_k+0][a_m]=av.x; As[a_k+1][a_m]=av.y; As[a_k+2][a_m]=av.z; As[a_k+3][a_m]=av.w;

        float4 bv = make_float4(0.f,0.f,0.f,0.f);
        const float* bp = Bm + (size_t)(k0 + b_k) * N + b_n;
        if (b_n + 0 < N) bv.x = bp[0];
        if (b_n + 1 < N) bv.y = bp[1];
        if (b_n + 2 < N) bv.z = bp[2];
        if (b_n + 3 < N) bv.w = bp[3];
        *(float4*)&Bs[b_k][b_n] = bv;

        __syncthreads();
        #pragma unroll
        for (int k = 0; k < 16; ++k) {
            const float4 a4 = *(const float4*)&As[k][my];
            const float4 b4 = *(const float4*)&Bs[k][nx];
            const float a[4] = {a4.x,a4.y,a4.z,a4.w};
            const float b[4] = {b4.x,b4.y,b4.z,b4.w};
            #pragma unroll
            for (int i = 0; i < 4; ++i)
                #pragma unroll
                for (int j = 0; j < 4; ++j)
                    acc[i][j] = fmaf(a[i], b[j], acc[i][j]);
        }
        __syncthreads();
    }

    #pragma unroll
    for (int i = 0; i < 4; ++i) {
        const int m = bm + my + i;
        if (m >= M) continue;
        #pragma unroll
        for (int j = 0; j < 4; ++j) {
            const int n = nx + j;
            if (n >= N) continue;
            C[(size_t)m * N + n] = acc[i][j] + bias[n];
        }
    }
}

// ---------------------------------------------------------------------------
// LayerNorm over 256 cols; OUT_SPLIT -> (Yh,Yl) bf16 split, else Yf f32.
// ---------------------------------------------------------------------------
template<bool RELU, bool OUT_SPLIT>
__global__ __launch_bounds__(256)
void ln_kernel(const float* __restrict__ X, const float* __restrict__ g,
               const float* __restrict__ b, float* __restrict__ Yf,
               u16* __restrict__ Yh, u16* __restrict__ Yl)
{
    const int row = blockIdx.x, tid = threadIdx.x;
    const float x = X[(size_t)row * D_MAIN + tid];
    __shared__ float red[4];
    const int lane = tid & 63, wid = tid >> 6;

    float s = x;
    #pragma unroll
    for (int off = 32; off; off >>= 1) s += __shfl_down(s, off, 64);
    if (lane == 0) red[wid] = s;
    __syncthreads();
    const float mean = (red[0] + red[1] + red[2] + red[3]) * (1.f / D_MAIN);
    __syncthreads();

    const float xm = x - mean;
    s = xm * xm;
    #pragma unroll
    for (int off = 32; off; off >>= 1) s += __shfl_down(s, off, 64);
    if (lane == 0) red[wid] = s;
    __syncthreads();
    const float var = (red[0] + red[1] + red[2] + red[3]) * (1.f / D_MAIN);

    float y = xm / sqrtf(var + LN_EPS) * g[tid] + b[tid];
    if (RELU) y = fmaxf(y, 0.f);
    if (OUT_SPLIT) {
        u16 h, l; split_f32(y, h, l);
        Yh[(size_t)row * D_MAIN + tid] = h;
        Yl[(size_t)row * D_MAIN + tid] = l;
    } else {
        Yf[(size_t)row * D_MAIN + tid] = y;
    }
}

// ---------------------------------------------------------------------------
// ||cand_k[n]||^2 from split representation
// ---------------------------------------------------------------------------
__global__ __launch_bounds__(64)
void cn2_kernel(const u16* __restrict__ ckh, const u16* __restrict__ ckl,
                float* __restrict__ out)
{
    const int row = blockIdx.x, lane = threadIdx.x;
    const ushort4 h4 = *(const ushort4*)(ckh + (size_t)row * D_MAIN + lane * 4);
    const ushort4 l4 = *(const ushort4*)(ckl + (size_t)row * D_MAIN + lane * 4);
    const float c0 = join_f32(h4.x, l4.x), c1 = join_f32(h4.y, l4.y);
    const float c2 = join_f32(h4.z, l4.z), c3 = join_f32(h4.w, l4.w);
    float s = c0*c0 + c1*c1 + c2*c2 + c3*c3;
    #pragma unroll
    for (int off = 32; off; off >>= 1) s += __shfl_down(s, off, 64);
    if (lane == 0) out[row] = s;
}

// ---------------------------------------------------------------------------
// conversions
// ---------------------------------------------------------------------------
__global__ __launch_bounds__(256)
void f32_to_split_kernel(const float* __restrict__ src, u16* __restrict__ hi,
                         u16* __restrict__ lo, int n)
{
    int i = blockIdx.x * 256 + threadIdx.x;
    if (i < n) {
        u16 h, l; split_f32(src[i], h, l);
        hi[i] = h; lo[i] = l;
    }
}

__global__ __launch_bounds__(256)
void transpose_split_kernel(const float* __restrict__ src, u16* __restrict__ dh,
                            u16* __restrict__ dl, int R, int C)
{
    int idx = blockIdx.x * 256 + threadIdx.x;
    if (idx < R * C) {
        const int r = idx / C, c = idx % C;
        u16 h, l; split_f32(src[idx], h, l);
        dh[(size_t)c * R + r] = h;
        dl[(size_t)c * R + r] = l;
    }
}

// ---------------------------------------------------------------------------
// Top-96 smallest per row on u16 monotone keys.
// Conflict-free histogram: hist[bin][64 replicas]; replica = tid&63 ->
// bank = replica%32, so a wave's 64 lanes always span all 32 banks with
// no same-address contention regardless of key distribution.
// ---------------------------------------------------------------------------
__global__ __launch_bounds__(1024)
void topk96_u16_kernel(const u16* __restrict__ keys, int* __restrict__ idx_out,
                       int* __restrict__ tiebuf, int* __restrict__ tiecnt,
                       int* __restrict__ lesscnt)
{
    const int row = blockIdx.x;
    const u16* krow = keys + (size_t)row * N_CAND;
    const int tid = threadIdx.x;
    const int rep = tid & 63;

    __shared__ unsigned hist[256 * 64];    // [bin*64 + rep], 64 KB
    __shared__ unsigned hsum[256];
    __shared__ unsigned sh_bin, sh_need;
    __shared__ int cntLess, cntEq;

    // ---- pass 1: high byte ----
    #pragma unroll
    for (int i = 0; i < 16; ++i) hist[tid + i * 1024] = 0;
    __syncthreads();
    for (int i = tid; i < N_CAND / 8; i += 1024) {
        const uint4 v = ((const uint4*)krow)[i];
        const unsigned w[4] = {v.x, v.y, v.z, v.w};
        #pragma unroll
        for (int e = 0; e < 4; ++e) {
            atomicAdd(&hist[(((w[e] >> 8) & 0xFFu)) * 64 + rep], 1u);
            atomicAdd(&hist[((w[e] >> 24)) * 64 + rep], 1u);
        }
    }
    __syncthreads();
    if (tid < 256) {        // staggered replica merge (conflict-free)
        unsigned s = 0;
        #pragma unroll
        for (int r = 0; r < 64; ++r) s += hist[tid * 64 + ((r + tid) & 63)];
        hsum[tid] = s;
    }
    __syncthreads();
    int need = CTX;
    if (tid < 64) {
        const unsigned b0 = hsum[tid*4+0], b1 = hsum[tid*4+1],
                       b2 = hsum[tid*4+2], b3 = hsum[tid*4+3];
        const unsigned lsum = b0 + b1 + b2 + b3;
        unsigned pre = lsum;
        #pragma unroll
        for (int off = 1; off < 64; off <<= 1) {
            const unsigned t = __shfl_up(pre, off, 64);
            if (tid >= off) pre += t;
        }
        const unsigned excl = pre - lsum;
        const unsigned nd = (unsigned)need;
        if (excl < nd && excl + lsum >= nd) {
            unsigned bin, rem;
            if      (excl + b0 >= nd)           { bin = tid*4+0; rem = nd - excl; }
            else if (excl + b0 + b1 >= nd)      { bin = tid*4+1; rem = nd - excl - b0; }
            else if (excl + b0 + b1 + b2 >= nd) { bin = tid*4+2; rem = nd - excl - b0 - b1; }
            else                                { bin = tid*4+3; rem = nd - excl - b0 - b1 - b2; }
            sh_bin = bin; sh_need = rem;
        }
    }
    __syncthreads();
    const unsigned hb = sh_bin;
    need = (int)sh_need;
    __syncthreads();

    // ---- pass 2: low byte among hb ----
    #pragma unroll
    for (int i = 0; i < 16; ++i) hist[tid + i * 1024] = 0;
    __syncthreads();
    for (int i = tid; i < N_CAND / 8; i += 1024) {
        const uint4 v = ((const uint4*)krow)[i];
        const unsigned w[4] = {v.x, v.y, v.z, v.w};
        #pragma unroll
        for (int e = 0; e < 4; ++e) {
            const unsigned k0 = w[e] & 0xFFFFu, k1 = w[e] >> 16;
            if ((k0 >> 8) == hb) atomicAdd(&hist[(k0 & 255u) * 64 + rep], 1u);
            if ((k1 >> 8) == hb) atomicAdd(&hist[(k1 & 255u) * 64 + rep], 1u);
        }
    }
    __syncthreads();
    if (tid < 256) {
        unsigned s = 0;
        #pragma unroll
        for (int r = 0; r < 64; ++r) s += hist[tid * 64 + ((r + tid) & 63)];
        hsum[tid] = s;
    }
    __syncthreads();
    if (tid < 64) {
        const unsigned b0 = hsum[tid*4+0], b1 = hsum[tid*4+1],
                       b2 = hsum[tid*4+2], b3 = hsum[tid*4+3];
        const unsigned lsum = b0 + b1 + b2 + b3;
        unsigned pre = lsum;
        #pragma unroll
        for (int off = 1; off < 64; off <<= 1) {
            const unsigned t = __shfl_up(pre, off, 64);
            if (tid >= off) pre += t;
        }
        const unsigned excl = pre - lsum;
        const unsigned nd = (unsigned)need;
        if (excl < nd && excl + lsum >= nd) {
            unsigned bin, rem;
            if      (excl + b0 >= nd)           { bin = tid*4+0; rem = nd - excl; }
            else if (excl + b0 + b1 >= nd)      { bin = tid*4+1; rem = nd - excl - b0; }
            else if (excl + b0 + b1 + b2 >= nd) { bin = tid*4+2; rem = nd - excl - b0 - b1; }
            else                                { bin = tid*4+3; rem = nd - excl - b0 - b1 - b2; }
            sh_bin = bin; sh_need = rem;
        }
    }
    __syncthreads();
    const unsigned T16 = (hb << 8) | sh_bin;
    need = (int)sh_need;

    if (tid == 0) { cntLess = 0; cntEq = 0; }
    __syncthreads();

    // ---- pass 3: collect strictly-less, buffer ties ----
    for (int i = tid; i < N_CAND / 8; i += 1024) {
        const uint4 v = ((const uint4*)krow)[i];
        const unsigned w[4] = {v.x, v.y, v.z, v.w};
        #pragma unroll
        for (int e = 0; e < 4; ++e) {
            const unsigned k0 = w[e] & 0xFFFFu, k1 = w[e] >> 16;
            const int n0 = i * 8 + e * 2, n1 = n0 + 1;
            if (k0 < T16) {
                const int p = atomicAdd(&cntLess, 1);
                idx_out[row * CTX + p] = n0;
            } else if (k0 == T16) {
                const int p = atomicAdd(&cntEq, 1);
                if (p < MAXTIE) tiebuf[(size_t)row * MAXTIE + p] = n0;
            }
            if (k1 < T16) {
                const int p = atomicAdd(&cntLess, 1);
                idx_out[row * CTX + p] = n1;
            } else if (k1 == T16) {
                const int p = atomicAdd(&cntEq, 1);
                if (p < MAXTIE) tiebuf[(size_t)row * MAXTIE + p] = n1;
            }
        }
    }
    __syncthreads();
    if (tid == 0) {
        lesscnt[row] = cntLess;
        tiecnt[row] = (cntEq < MAXTIE) ? cntEq : MAXTIE;
    }
}

// ---------------------------------------------------------------------------
// Exact fp32 tie-break among u16-equal candidates (cand_k reconstructed)
// ---------------------------------------------------------------------------
__global__ __launch_bounds__(256)
void tiebreak_kernel(const float* __restrict__ k_x, const u16* __restrict__ ckh,
                     const u16* __restrict__ ckl, const float* __restrict__ ck2,
                     const int* __restrict__ tiebuf, const int* __restrict__ tiecnt,
                     const int* __restrict__ lesscnt, int* __restrict__ idx_out)
{
    const int row = blockIdx.x;
    const int tid = threadIdx.x;
    const int T = tiecnt[row];
    const int less = lesscnt[row];
    const int need = CTX - less;
    if (need <= 0) return;

    if (T <= need) {
        for (int t = tid; t < T; t += 256)
            idx_out[row * CTX + less + t] = tiebuf[(size_t)row * MAXTIE + t];
        return;
    }

    __shared__ float sv[MAXTIE];
    const float* kv = k_x + (size_t)row * D_MAIN;
    for (int t = tid; t < T; t += 256) {
        const int c = tiebuf[(size_t)row * MAXTIE + t];
        const u16* ch = ckh + (size_t)c * D_MAIN;
        const u16* cl = ckl + (size_t)c * D_MAIN;
        float s = 0.f;
        for (int d = 0; d < D_MAIN; d += 4) {
            const float4 a = *(const float4*)(kv + d);
            const ushort4 h4 = *(const ushort4*)(ch + d);
            const ushort4 l4 = *(const ushort4*)(cl + d);
            s += a.x * join_f32(h4.x, l4.x) + a.y * join_f32(h4.y, l4.y)
               + a.z * join_f32(h4.z, l4.z) + a.w * join_f32(h4.w, l4.w);
        }
        sv[t] = ck2[c] - 2.f * s;
    }
    __syncthreads();

    __shared__ unsigned hist[256];
    __shared__ unsigned sh_bin, sh_need;
    unsigned prefix = 0;
    int plen = 0;
    int nd = need;
    for (int pass = 0; pass < 4; ++pass) {
        const int shift = 24 - 8 * pass;
        hist[tid] = 0;
        __syncthreads();
        for (int t = tid; t < T; t += 256) {
            const unsigned u = f2u_mono(sv[t]);
            if (plen == 0 || (u >> (32 - plen)) == prefix)
                atomicAdd(&hist[(u >> shift) & 255u], 1u);
        }
        __syncthreads();
        if (tid == 0) {
            int cum = 0;
            for (int bb = 0; bb < 256; ++bb) {
                const int h = (int)hist[bb];
                if (cum + h >= nd) { sh_bin = (unsigned)bb; sh_need = (unsigned)(nd - cum); break; }
                cum += h;
            }
        }
        __syncthreads();
        prefix = (prefix << 8) | sh_bin;
        nd = (int)sh_need;
        plen += 8;
        __syncthreads();
    }
    const unsigned Tf = prefix;
    const int nl2 = need - nd;
    __shared__ int c1, c2;
    if (tid == 0) { c1 = 0; c2 = 0; }
    __syncthreads();
    for (int t = tid; t < T; t += 256) {
        const unsigned u = f2u_mono(sv[t]);
        if (u < Tf) {
            const int p = atomicAdd(&c1, 1);
            idx_out[row * CTX + less + p] = tiebuf[(size_t)row * MAXTIE + t];
        } else if (u == Tf) {
            const int p = atomicAdd(&c2, 1);
            if (p < nd) idx_out[row * CTX + less + nl2 + p] = tiebuf[(size_t)row * MAXTIE + t];
        }
    }
}

// ---------------------------------------------------------------------------
// Exact fp32 partial distance for selected 96 (cand_k reconstructed)
// ---------------------------------------------------------------------------
__global__ __launch_bounds__(256)
void sim_exact_kernel(const float* __restrict__ k_x, const u16* __restrict__ ckh,
                      const u16* __restrict__ ckl, const float* __restrict__ ck2,
                      const int* __restrict__ idx, float* __restrict__ sval)
{
    const int bc = blockIdx.x * 4 + (threadIdx.x >> 6);
    const int lane = threadIdx.x & 63;
    const int b = bc / CTX;
    const int id = idx[bc];
    const float4 kv = *(const float4*)(k_x + (size_t)b * D_MAIN + lane * 4);
    const ushort4 h4 = *(const ushort4*)(ckh + (size_t)id * D_MAIN + lane * 4);
    const ushort4 l4 = *(const ushort4*)(ckl + (size_t)id * D_MAIN + lane * 4);
    float s = kv.x * join_f32(h4.x, l4.x) + kv.y * join_f32(h4.y, l4.y)
            + kv.z * join_f32(h4.z, l4.z) + kv.w * join_f32(h4.w, l4.w);
    #pragma unroll
    for (int off = 32; off; off >>= 1) s += __shfl_down(s, off, 64);
    if (lane == 0) sval[bc] = ck2[id] - 2.f * s;
}

// ---------------------------------------------------------------------------
// softmax over 96 slots
// ---------------------------------------------------------------------------
__global__ __launch_bounds__(128)
void softmax96_kernel(const float* __restrict__ sval, float* __restrict__ probs)
{
    __shared__ float sh[128];
    const int row = blockIdx.x, tid = threadIdx.x;
    const float v = (tid < CTX) ? -sval[row * CTX + tid] : -1e30f;
    sh[tid] = v;
    __syncthreads();
    for (int s = 64; s > 0; s >>= 1) {
        if (tid < s) sh[tid] = fmaxf(sh[tid], sh[tid + s]);
        __syncthreads();
    }
    const float m = sh[0];
    __syncthreads();
    const float e = (tid < CTX) ? __expf(v - m) : 0.f;
    sh[tid] = e;
    __syncthreads();
    for (int s = 64; s > 0; s >>= 1) {
        if (tid < s) sh[tid] += sh[tid + s];
        __syncthreads();
    }
    if (tid < CTX) probs[row * CTX + tid] = e / sh[0];
}

// ---------------------------------------------------------------------------
// diff split (cand_k reconstructed)
// ---------------------------------------------------------------------------
__global__ __launch_bounds__(256)
void build_diff_kernel(const float* __restrict__ k_x, const u16* __restrict__ ckh,
                       const u16* __restrict__ ckl, const int* __restrict__ idx,
                       u16* __restrict__ dh, u16* __restrict__ dl)
{
    const int bc = blockIdx.x;
    const int b = bc / CTX;
    const int d = threadIdx.x;
    const int id = idx[bc];
    const float c = join_f32(ckh[(size_t)id * D_MAIN + d], ckl[(size_t)id * D_MAIN + d]);
    const float v = k_x[(size_t)b * D_MAIN + d] - c;
    u16 h, l; split_f32(v, h, l);
    dh[(size_t)bc * D_MAIN + d] = h;
    dl[(size_t)bc * D_MAIN + d] = l;
}

// ---------------------------------------------------------------------------
// h[b,d] += sum_c probs[b,c] * (label_emb[cand_y[idx[b,c]], d] + v[(b,c), d])
// ---------------------------------------------------------------------------
__global__ __launch_bounds__(256)
void mix_reduce_kernel(float* __restrict__ h, const float* __restrict__ v,
                       const float* __restrict__ probs, const int* __restrict__ idx,
                       const int* __restrict__ cy, const float* __restrict__ label_emb)
{
    const int b = blockIdx.x;
    const int d = threadIdx.x;
    float acc = 0.f;
    for (int c = 0; c < CTX; ++c) {
        const int bc = b * CTX + c;
        const int id = idx[bc];
        const int y = cy[id];
        const float val = label_emb[(size_t)y * D_MAIN + d] + v[(size_t)bc * D_MAIN + d];
        acc = fmaf(probs[bc], val, acc);
    }
    h[(size_t)b * D_MAIN + d] += acc;
}

// ---------------------------------------------------------------------------
// host-side orchestration
// ---------------------------------------------------------------------------
static inline dim3 g128(int M, int N) {
    return dim3((unsigned)((N + 127) / 128), (unsigned)((M + 127) / 128));
}

struct EncW {
    const u16 *WlinTh, *WlinTl, *e0W1Th, *e0W1Tl, *e0W2Th, *e0W2Tl,
              *e1W1Th, *e1W1Tl, *e1W2Th, *e1W2Tl, *KWTh, *KWTl;
    const float *b_lin, *e0b1, *e0b2, *e1g, *e1b, *e1b1, *e1b2, *mixg, *mixb, *Kb;
};

// encode R rows; KF: also write K as f32 (x rows need it; candidates don't)
template<bool KF>
static void encode_rows_split(const u16* Xh, const u16* Xl, int R, const EncW& w,
                              float* H, u16* Hh, u16* Hl, u16* Th, u16* Tl,
                              u16* TNh, u16* TNl, float* Kf, u16* Kh, u16* Kl,
                              hipStream_t stream)
{
    dim3 blk(256);
    gemm_split_nt<false,true,false,false,true,true,false,true><<<g128(R, D_MAIN), blk, 0, stream>>>(
        Xh, Xl, w.WlinTh, w.WlinTl, w.b_lin, nullptr, H, Hh, Hl, R, D_MAIN, D_IN);
    gemm_split_nt<true,true,false,false,false,true,false,true><<<g128(R, D_BLOCK), blk, 0, stream>>>(
        Hh, Hl, w.e0W1Th, w.e0W1Tl, w.e0b1, nullptr, nullptr, Th, Tl, R, D_BLOCK, D_MAIN);
    gemm_split_nt<false,true,true,false,true,false,false,true><<<g128(R, D_MAIN), blk, 0, stream>>>(
        Th, Tl, w.e0W2Th, w.e0W2Tl, w.e0b2, H, H, nullptr, nullptr, R, D_MAIN, D_BLOCK);
    ln_kernel<false,true><<<R, 256, 0, stream>>>(H, w.e1g, w.e1b, nullptr, TNh, TNl);
    gemm_split_nt<true,true,false,false,false,true,false,true><<<g128(R, D_BLOCK), blk, 0, stream>>>(
        TNh, TNl, w.e1W1Th, w.e1W1Tl, w.e1b1, nullptr, nullptr, Th, Tl, R, D_BLOCK, D_MAIN);
    gemm_split_nt<false,true,true,false,true,false,false,true><<<g128(R, D_MAIN), blk, 0, stream>>>(
        Th, Tl, w.e1W2Th, w.e1W2Tl, w.e1b2, H, H, nullptr, nullptr, R, D_MAIN, D_BLOCK);
    ln_kernel<false,true><<<R, 256, 0, stream>>>(H, w.mixg, w.mixb, nullptr, TNh, TNl);
    if (KF)
        gemm_split_nt<false,true,false,false,true,true,false,true><<<g128(R, D_MAIN), blk, 0, stream>>>(
            TNh, TNl, w.KWTh, w.KWTl, w.Kb, nullptr, Kf, Kh, Kl, R, D_MAIN, D_MAIN);
    else
        gemm_split_nt<false,true,false,false,false,true,false,true><<<g128(R, D_MAIN), blk, 0, stream>>>(
            TNh, TNl, w.KWTh, w.KWTl, w.Kb, nullptr, nullptr, Kh, Kl, R, D_MAIN, D_MAIN);
}

extern "C" void kernel_launch(void* const* d_in, const int* in_sizes, int n_in,
                              void* d_out, int out_size, void* d_ws, size_t ws_size,
                              hipStream_t stream)
{
    const float* x        = (const float*)d_in[0];
    const float* cand_x   = (const float*)d_in[1];
    const int*   cand_y   = (const int*)  d_in[2];
    const float* W_lin    = (const float*)d_in[4];
    const float* b_lin    = (const float*)d_in[5];
    const float* e0W1     = (const float*)d_in[6];
    const float* e0b1     = (const float*)d_in[7];
    const float* e0W2     = (const float*)d_in[8];
    const float* e0b2     = (const float*)d_in[9];
    const float* e1g      = (const float*)d_in[10];
    const float* e1b      = (const float*)d_in[11];
    const float* e1W1     = (const float*)d_in[12];
    const float* e1b1     = (const float*)d_in[13];
    const float* e1W2     = (const float*)d_in[14];
    const float* e1b2     = (const float*)d_in[15];
    const float* mixg     = (const float*)d_in[16];
    const float* mixb     = (const float*)d_in[17];
    const float* K_W      = (const float*)d_in[18];
    const float* K_b      = (const float*)d_in[19];
    const float* label_emb= (const float*)d_in[20];
    const float* T_W1     = (const float*)d_in[21];
    const float* T_b1     = (const float*)d_in[22];
    const float* T_W2     = (const float*)d_in[23];
    const float* p0g      = (const float*)d_in[24];
    const float* p0b      = (const float*)d_in[25];
    const float* p0W1     = (const float*)d_in[26];
    const float* p0b1     = (const float*)d_in[27];
    const float* p0W2     = (const float*)d_in[28];
    const float* p0b2     = (const float*)d_in[29];
    const float* p1g      = (const float*)d_in[30];
    const float* p1b      = (const float*)d_in[31];
    const float* p1W1     = (const float*)d_in[32];
    const float* p1b1     = (const float*)d_in[33];
    const float* p1W2     = (const float*)d_in[34];
    const float* p1b2     = (const float*)d_in[35];
    const float* headg    = (const float*)d_in[36];
    const float* headb    = (const float*)d_in[37];
    const float* head_W   = (const float*)d_in[38];
    const float* head_bias= (const float*)d_in[39];

    char* ws = (char*)d_ws;
    size_t off = 0;
    auto alloc = [&](size_t bytes) -> char* {
        char* p = ws + off;
        off += (bytes + 255) & ~(size_t)255;
        return p;
    };

    // persistent (~103 MB; cand_k f32 dropped — reconstructed from split)
    u16* cand_k_h  = (u16*)alloc((size_t)N_CAND * D_MAIN * 2);
    u16* cand_k_l  = (u16*)alloc((size_t)N_CAND * D_MAIN * 2);
    u16* cand_x_h  = (u16*)alloc((size_t)N_CAND * D_IN * 2);
    u16* cand_x_l  = (u16*)alloc((size_t)N_CAND * D_IN * 2);
    u16* x_h       = (u16*)alloc((size_t)B_ROWS * D_IN * 2);
    u16* x_l       = (u16*)alloc((size_t)B_ROWS * D_IN * 2);
    float* ck2     = (float*)alloc((size_t)N_CAND * 4);
    float* h_x     = (float*)alloc((size_t)B_ROWS * D_MAIN * 4);
    float* tn_x    = (float*)alloc((size_t)B_ROWS * D_MAIN * 4);
    float* t_x     = (float*)alloc((size_t)B_ROWS * D_BLOCK * 4);
    float* k_x     = (float*)alloc((size_t)B_ROWS * D_MAIN * 4);
    u16* xe_Hh     = (u16*)alloc((size_t)B_ROWS * D_MAIN * 2);
    u16* xe_Hl     = (u16*)alloc((size_t)B_ROWS * D_MAIN * 2);
    u16* xe_Th     = (u16*)alloc((size_t)B_ROWS * D_BLOCK * 2);
    u16* xe_Tl     = (u16*)alloc((size_t)B_ROWS * D_BLOCK * 2);
    u16* xe_TNh    = (u16*)alloc((size_t)B_ROWS * D_MAIN * 2);
    u16* xe_TNl    = (u16*)alloc((size_t)B_ROWS * D_MAIN * 2);
    u16* k_x_h     = (u16*)alloc((size_t)B_ROWS * D_MAIN * 2);
    u16* k_x_l     = (u16*)alloc((size_t)B_ROWS * D_MAIN * 2);
    int*   idx     = (int*)  alloc((size_t)B_ROWS * CTX * 4);
    float* sval    = (float*)alloc((size_t)B_ROWS * CTX * 4);
    float* probs   = (float*)alloc((size_t)B_ROWS * CTX * 4);
    int* tiebuf    = (int*)  alloc((size_t)B_ROWS * MAXTIE * 4);
    int* tiecnt    = (int*)  alloc((size_t)B_ROWS * 4);
    int* lesscnt   = (int*)  alloc((size_t)B_ROWS * 4);

    u16* WlinTh = (u16*)alloc((size_t)D_IN  * D_MAIN * 2);
    u16* WlinTl = (u16*)alloc((size_t)D_IN  * D_MAIN * 2);
    u16* e0W1Th = (u16*)alloc((size_t)D_MAIN* D_BLOCK * 2);
    u16* e0W1Tl = (u16*)alloc((size_t)D_MAIN* D_BLOCK * 2);
    u16* e0W2Th = (u16*)alloc((size_t)D_BLOCK*D_MAIN * 2);
    u16* e0W2Tl = (u16*)alloc((size_t)D_BLOCK*D_MAIN * 2);
    u16* e1W1Th = (u16*)alloc((size_t)D_MAIN* D_BLOCK * 2);
    u16* e1W1Tl = (u16*)alloc((size_t)D_MAIN* D_BLOCK * 2);
    u16* e1W2Th = (u16*)alloc((size_t)D_BLOCK*D_MAIN * 2);
    u16* e1W2Tl = (u16*)alloc((size_t)D_BLOCK*D_MAIN * 2);
    u16* KWTh   = (u16*)alloc((size_t)D_MAIN* D_MAIN * 2);
    u16* KWTl   = (u16*)alloc((size_t)D_MAIN* D_MAIN * 2);
    u16* TW1Th  = (u16*)alloc((size_t)D_MAIN* D_BLOCK * 2);
    u16* TW1Tl  = (u16*)alloc((size_t)D_MAIN* D_BLOCK * 2);
    u16* TW2Th  = (u16*)alloc((size_t)D_BLOCK*D_MAIN * 2);
    u16* TW2Tl  = (u16*)alloc((size_t)D_BLOCK*D_MAIN * 2);

    const size_t pool_avail = (ws_size > off) ? (ws_size - off) : 0;
    int rc_enc = (int)(pool_avail / 5120);
    if (rc_enc > 25000) rc_enc = 25000;
    if (rc_enc < 6250)  rc_enc = 6250;
    int mb_ch = (int)(pool_avail / ((size_t)2 * N_CAND));
    if (mb_ch > B_ROWS) mb_ch = B_ROWS;
    if (mb_ch < 128)    mb_ch = 128;
    int bb_ch = (int)(pool_avail / ((size_t)CTX * 3072));
    if (bb_ch > B_ROWS) bb_ch = B_ROWS;
    if (bb_ch < 64)     bb_ch = 64;

    char* pool = ws + off;
    dim3 blk(256);

    // 0) conversions
    {
        f32_to_split_kernel<<<(B_ROWS*D_IN + 255)/256, blk, 0, stream>>>(x, x_h, x_l, B_ROWS*D_IN);
        f32_to_split_kernel<<<(N_CAND*D_IN + 255)/256, blk, 0, stream>>>(cand_x, cand_x_h, cand_x_l, N_CAND*D_IN);
        auto tr = [&](const float* s, u16* dh, u16* dl, int R, int C) {
            transpose_split_kernel<<<(R*C + 255)/256, blk, 0, stream>>>(s, dh, dl, R, C);
        };
        tr(W_lin, WlinTh, WlinTl, D_IN,   D_MAIN);
        tr(e0W1,  e0W1Th, e0W1Tl, D_MAIN, D_BLOCK);
        tr(e0W2,  e0W2Th, e0W2Tl, D_BLOCK,D_MAIN);
        tr(e1W1,  e1W1Th, e1W1Tl, D_MAIN, D_BLOCK);
        tr(e1W2,  e1W2Th, e1W2Tl, D_BLOCK,D_MAIN);
        tr(K_W,   KWTh,   KWTl,   D_MAIN, D_MAIN);
        tr(T_W1,  TW1Th,  TW1Tl,  D_MAIN, D_BLOCK);
        tr(T_W2,  TW2Th,  TW2Tl,  D_BLOCK,D_MAIN);
    }

    EncW w = { WlinTh, WlinTl, e0W1Th, e0W1Tl, e0W2Th, e0W2Tl,
               e1W1Th, e1W1Tl, e1W2Th, e1W2Tl, KWTh, KWTl,
               b_lin, e0b1, e0b2, e1g, e1b, e1b1, e1b2, mixg, mixb, K_b };

    // 1) encode candidates -> cand_k split only
    for (int r0 = 0; r0 < N_CAND; r0 += rc_enc) {
        const int R = (N_CAND - r0 < rc_enc) ? (N_CAND - r0) : rc_enc;
        char* p = pool;
        float* Hc = (float*)p;        p += (size_t)rc_enc * D_MAIN * 4;
        u16* Hh  = (u16*)p;           p += (size_t)rc_enc * D_MAIN * 2;
        u16* Hl  = (u16*)p;           p += (size_t)rc_enc * D_MAIN * 2;
        u16* Th  = (u16*)p;           p += (size_t)rc_enc * D_BLOCK * 2;
        u16* Tl  = (u16*)p;           p += (size_t)rc_enc * D_BLOCK * 2;
        u16* TNh = (u16*)p;           p += (size_t)rc_enc * D_MAIN * 2;
        u16* TNl = (u16*)p;
        encode_rows_split<false>(cand_x_h + (size_t)r0 * D_IN, cand_x_l + (size_t)r0 * D_IN,
                                 R, w, Hc, Hh, Hl, Th, Tl, TNh, TNl,
                                 nullptr,
                                 cand_k_h + (size_t)r0 * D_MAIN,
                                 cand_k_l + (size_t)r0 * D_MAIN, stream);
    }

    // 2) encode x -> h_x f32, k_x f32 + split
    encode_rows_split<true>(x_h, x_l, B_ROWS, w, h_x, xe_Hh, xe_Hl, xe_Th, xe_Tl,
                            xe_TNh, xe_TNl, k_x, k_x_h, k_x_l, stream);

    // 3) candidate norms (reconstructed)
    cn2_kernel<<<N_CAND, 64, 0, stream>>>(cand_k_h, cand_k_l, ck2);

    // 4+5) distance keys (u16) + top-96 select
    for (int m0 = 0; m0 < B_ROWS; m0 += mb_ch) {
        const int R = (B_ROWS - m0 < mb_ch) ? (B_ROWS - m0) : mb_ch;
        u16* s_keys = (u16*)pool;
        gemm_split_nt<false,false,false,true,false,false,false,true><<<g128(R, N_CAND), blk, 0, stream>>>(
            k_x_h + (size_t)m0 * D_MAIN, k_x_l + (size_t)m0 * D_MAIN,
            cand_k_h, cand_k_l, ck2, nullptr, nullptr, s_keys, nullptr,
            R, N_CAND, D_MAIN);
        topk96_u16_kernel<<<R, 1024, 0, stream>>>(
            s_keys, idx + m0 * CTX, tiebuf + (size_t)m0 * MAXTIE,
            tiecnt + m0, lesscnt + m0);
    }

    // 5b) exact fp32 tie-break
    tiebreak_kernel<<<B_ROWS, 256, 0, stream>>>(k_x, cand_k_h, cand_k_l, ck2,
                                                tiebuf, tiecnt, lesscnt, idx);

    // 5c) exact fp32 sval for selected 96
    sim_exact_kernel<<<B_ROWS * CTX / 4, 256, 0, stream>>>(k_x, cand_k_h, cand_k_l,
                                                           ck2, idx, sval);

    // 6) softmax
    softmax96_kernel<<<B_ROWS, 128, 0, stream>>>(sval, probs);

    // 7-10) T-MLP + mix
    for (int b0 = 0; b0 < B_ROWS; b0 += bb_ch) {
        const int rows = (B_ROWS - b0 < bb_ch) ? (B_ROWS - b0) : bb_ch;
        const int R = rows * CTX;
        char* p = pool;
        u16* dh = (u16*)p;  p += (size_t)bb_ch * CTX * D_MAIN * 2;
        u16* dl = (u16*)p;  p += (size_t)bb_ch * CTX * D_MAIN * 2;
        u16* th = (u16*)p;  p += (size_t)bb_ch * CTX * D_BLOCK * 2;
        float* v = (float*)p;
        build_diff_kernel<<<R, 256, 0, stream>>>(
            k_x + (size_t)b0 * D_MAIN, cand_k_h, cand_k_l, idx + b0 * CTX, dh, dl);
        gemm_split_nt<true,true,false,false,false,false,true,true><<<g128(R, D_BLOCK), blk, 0, stream>>>(
            dh, dl, TW1Th, TW1Tl, T_b1, nullptr, nullptr, th, nullptr, R, D_BLOCK, D_MAIN);
        gemm_split_nt<false,false,false,false,true,false,false,false><<<g128(R, D_MAIN), blk, 0, stream>>>(
            th, nullptr, TW2Th, TW2Tl, nullptr, nullptr, v, nullptr, nullptr, R, D_MAIN, D_BLOCK);
        mix_reduce_kernel<<<rows, 256, 0, stream>>>(
            h_x + (size_t)b0 * D_MAIN, v, probs + b0 * CTX, idx + b0 * CTX,
            cand_y, label_emb);
    }

    // 11) post blocks (fp32)
    ln_kernel<false,false><<<B_ROWS, 256, 0, stream>>>(h_x, p0g, p0b, tn_x, nullptr, nullptr);
    gemm128<true, true,false><<<g128(B_ROWS, D_BLOCK), blk, 0, stream>>>(tn_x, p0W1, p0b1, nullptr, t_x, B_ROWS, D_BLOCK, D_MAIN);
    gemm128<false,true,true ><<<g128(B_ROWS, D_MAIN), blk, 0, stream>>>(t_x, p0W2, p0b2, h_x, h_x, B_ROWS, D_MAIN, D_BLOCK);
    ln_kernel<false,false><<<B_ROWS, 256, 0, stream>>>(h_x, p1g, p1b, tn_x, nullptr, nullptr);
    gemm128<true, true,false><<<g128(B_ROWS, D_BLOCK), blk, 0, stream>>>(tn_x, p1W1, p1b1, nullptr, t_x, B_ROWS, D_BLOCK, D_MAIN);
    gemm128<false,true,true ><<<g128(B_ROWS, D_MAIN), blk, 0, stream>>>(t_x, p1W2, p1b2, h_x, h_x, B_ROWS, D_MAIN, D_BLOCK);

    // 12) head (fp32)
    ln_kernel<true,false><<<B_ROWS, 256, 0, stream>>>(h_x, headg, headb, tn_x, nullptr, nullptr);
    gemm_head<<<dim3(1, (B_ROWS + 63) / 64), blk, 0, stream>>>(
        tn_x, head_W, head_bias, (float*)d_out, B_ROWS, N_OUT, D_MAIN);
}